// Round 2
// baseline (179.256 us; speedup 1.0000x reference)
//
#include <hip/hip_runtime.h>
#include <hip/hip_fp16.h>
#include <math.h>

#define DIMN (1 << 20)   // 2^20 per batch row
// d_out layout: [2][16][DIMN] float32 (real block then imag block).
// d_ws  layout (fp16 path): [2][16][DIMN] __half.

__device__ __forceinline__ void bf(float& a, float& b) { float s = a + b; b = a - b; a = s; }

__device__ __forceinline__ void bf4(float4& a, float4& b) {
    bf(a.x, b.x); bf(a.y, b.y); bf(a.z, b.z); bf(a.w, b.w);
}

// WHT over 10 bits; 16 values/lane as 4 float4. element = r*256 + lane*4 + s
__device__ __forceinline__ void wht10_f4(float4 v[4], int lane) {
    #pragma unroll
    for (int r = 0; r < 4; r++) {
        bf(v[r].x, v[r].y); bf(v[r].z, v[r].w);   // bit0
        bf(v[r].x, v[r].z); bf(v[r].y, v[r].w);   // bit1
    }
    #pragma unroll
    for (int m = 1; m <= 32; m <<= 1) {           // bits 2..7 (lane bits)
        float sgn = (lane & m) ? -1.0f : 1.0f;
        #pragma unroll
        for (int r = 0; r < 4; r++) {
            float px = __shfl_xor(v[r].x, m);
            float py = __shfl_xor(v[r].y, m);
            float pz = __shfl_xor(v[r].z, m);
            float pw = __shfl_xor(v[r].w, m);
            v[r].x = fmaf(sgn, v[r].x, px);
            v[r].y = fmaf(sgn, v[r].y, py);
            v[r].z = fmaf(sgn, v[r].z, pz);
            v[r].w = fmaf(sgn, v[r].w, pw);
        }
    }
    bf4(v[0], v[1]); bf4(v[2], v[3]);             // bit8
    bf4(v[0], v[2]); bf4(v[1], v[3]);             // bit9
}

// WHT over 10 bits; 16 scalars/lane. element h = r*64 + lane
__device__ __forceinline__ void wht10_s(float v[16], int lane) {
    #pragma unroll
    for (int m = 1; m <= 32; m <<= 1) {           // h bits 0..5
        float sgn = (lane & m) ? -1.0f : 1.0f;
        #pragma unroll
        for (int r = 0; r < 16; r++) {
            float p = __shfl_xor(v[r], m);
            v[r] = fmaf(sgn, v[r], p);
        }
    }
    #pragma unroll
    for (int s = 1; s < 16; s <<= 1) {            // h bits 6..9
        #pragma unroll
        for (int r = 0; r < 16; r++) {
            if (!(r & s)) bf(v[r], v[r ^ s]);
        }
    }
}

// ============================ fp16 path ============================

// Pass 1: fp32 in (two arrays) -> low-10 WHT -> fp16 out (one array)
__global__ __launch_bounds__(256) void pass1_h_kernel(const float* __restrict__ srcA,
                                                      const float* __restrict__ srcB,
                                                      __half* __restrict__ dst) {
    const int tid  = threadIdx.x;
    const int lane = tid & 63;
    const int w    = tid >> 6;
    const int rt0  = blockIdx.x * 16 + w * 4;
    const float* src = (rt0 < 16384) ? (srcA + (size_t)rt0 * 1024)
                                     : (srcB + (size_t)(rt0 - 16384) * 1024);
    __half* d = dst + (size_t)rt0 * 1024;

    float4 v[4][4];
    #pragma unroll
    for (int rr = 0; rr < 4; rr++)
        #pragma unroll
        for (int r = 0; r < 4; r++)
            v[rr][r] = *(const float4*)(src + rr * 1024 + r * 256 + lane * 4);

    #pragma unroll
    for (int rr = 0; rr < 4; rr++) {
        wht10_f4(v[rr], lane);
        #pragma unroll
        for (int r = 0; r < 4; r++) {
            union { __half2 h2[2]; float2 f2; } u;
            u.h2[0] = __float22half2_rn(make_float2(v[rr][r].x * 0.03125f, v[rr][r].y * 0.03125f));
            u.h2[1] = __float22half2_rn(make_float2(v[rr][r].z * 0.03125f, v[rr][r].w * 0.03125f));
            *(float2*)(d + rr * 1024 + r * 256 + lane * 4) = u.f2;
        }
    }
}

// Pass 3: fp16 in -> low-10 WHT -> fp32 out
__global__ __launch_bounds__(256) void pass3_h_kernel(const __half* __restrict__ src,
                                                      float* __restrict__ dst) {
    const int tid  = threadIdx.x;
    const int lane = tid & 63;
    const int w    = tid >> 6;
    const int rt0  = blockIdx.x * 16 + w * 4;
    const __half* s = src + (size_t)rt0 * 1024;
    float* d = dst + (size_t)rt0 * 1024;

    float4 v[4][4];
    #pragma unroll
    for (int rr = 0; rr < 4; rr++)
        #pragma unroll
        for (int r = 0; r < 4; r++) {
            union { __half2 h2[2]; float2 f2; } u;
            u.f2 = *(const float2*)(s + rr * 1024 + r * 256 + lane * 4);
            float2 lo = __half22float2(u.h2[0]);
            float2 hi = __half22float2(u.h2[1]);
            v[rr][r] = make_float4(lo.x, lo.y, hi.x, hi.y);
        }

    #pragma unroll
    for (int rr = 0; rr < 4; rr++) {
        wht10_f4(v[rr], lane);
        #pragma unroll
        for (int r = 0; r < 4; r++) {
            float4 o;
            o.x = v[rr][r].x * 0.03125f;
            o.y = v[rr][r].y * 0.03125f;
            o.z = v[rr][r].z * 0.03125f;
            o.w = v[rr][r].w * 0.03125f;
            *(float4*)(d + rr * 1024 + r * 256 + lane * 4) = o;
        }
    }
}

// Pass 2 (fp16, in place in ws): high-10 WHT, rotate, high-10 WHT.
// Tile: 1024 h-rows x 16 columns x {re,im} as half = 64 KiB LDS.
// LDS word = __half2 holding column pair {2k, 2k+1}. 512 threads, 8 waves;
// wave w owns column pair w.
__global__ __launch_bounds__(512) void pass2_h_kernel(__half* __restrict__ buf,
                                                      const float* __restrict__ tptr) {
    __shared__ __align__(16) float tile[2][1024][8];   // 8 words = 16 half columns
    const int tid  = threadIdx.x;
    const int lane = tid & 63;
    const int w    = tid >> 6;

    // XCD-chunked swizzle (1024 wgs, 1024 % 8 == 0 -> bijective)
    int wg  = blockIdx.x;
    int swz = (wg & 7) * 128 + (wg >> 3);
    const int b  = swz >> 6;          // batch 0..15
    const int g  = swz & 63;          // column group 0..63
    const int c0 = g * 16;
    const float tval = tptr[0];

    __half* baseR = buf + (size_t)b * DIMN;
    __half* baseI = buf + (size_t)16 * DIMN + (size_t)b * DIMN;

    // ---- stage-in: coalesced global (16B/thread) -> swizzled LDS ----
    float4 tmp[2][4];
    #pragma unroll
    for (int comp = 0; comp < 2; comp++) {
        const __half* src = comp ? baseI : baseR;
        #pragma unroll
        for (int it = 0; it < 4; it++) {
            int f = it * 512 + tid;
            int h = f >> 1, q = f & 1;
            tmp[comp][it] = *(const float4*)(src + (size_t)h * 1024 + c0 + q * 8);
        }
    }
    #pragma unroll
    for (int comp = 0; comp < 2; comp++) {
        #pragma unroll
        for (int it = 0; it < 4; it++) {
            int f = it * 512 + tid;
            int h = f >> 1, q = f & 1;
            int e = (h >> 2) & 7;
            int elo = e & 3;
            float4 val = tmp[comp][it];
            // out[p] = val[p ^ elo] via 2 conditional swaps
            bool s0 = (elo & 1) != 0;
            float x1 = s0 ? val.y : val.x, y1 = s0 ? val.x : val.y;
            float z1 = s0 ? val.w : val.z, w1 = s0 ? val.z : val.w;
            bool s1 = (elo & 2) != 0;
            float x2 = s1 ? z1 : x1, y2 = s1 ? w1 : y1;
            float z2 = s1 ? x1 : z1, w2 = s1 ? y1 : w1;
            int qp = q ^ (e >> 2);
            *(float4*)&tile[comp][h][qp * 4] = make_float4(x2, y2, z2, w2);
        }
    }
    __syncthreads();

    // ---- LDS -> registers: wave w reads word (column pair) w, swizzled ----
    float vr[2][16], vi[2][16];
    #pragma unroll
    for (int r = 0; r < 16; r++) {
        int h = r * 64 + lane;
        int e = (lane >> 2) & 7;      // == (h>>2)&7 since (r*64>>2)&7 == 0
        int wp = w ^ e;
        union { float f; __half2 h2; } ur, ui;
        ur.f = tile[0][h][wp];
        ui.f = tile[1][h][wp];
        float2 fr = __half22float2(ur.h2);
        float2 fi = __half22float2(ui.h2);
        vr[0][r] = fr.x; vr[1][r] = fr.y;
        vi[0][r] = fi.x; vi[1][r] = fi.y;
    }

    // ---- WHT1-high, scale+rotate, WHT2-high ----
    const int pcl = __popc(lane);
    #pragma unroll
    for (int cc = 0; cc < 2; cc++) {
        wht10_s(vr[cc], lane);
        wht10_s(vi[cc], lane);
        const int cg = c0 + 2 * w + cc;          // full low-10 column index
        const int pbase = pcl + __popc(cg);
        float csk[5], snk[5];
        #pragma unroll
        for (int k = 0; k < 5; k++) {
            float ang = tval * (float)(20 - 2 * (pbase + k));
            sincosf(ang, &snk[k], &csk[k]);
        }
        #pragma unroll
        for (int r = 0; r < 16; r++) {
            const int pr = __popc(r);
            float cv = csk[pr], sv = snk[pr];
            float xr = vr[cc][r] * 0.03125f;
            float xi = vi[cc][r] * 0.03125f;
            vr[cc][r] = fmaf(cv, xr, sv * xi);
            vi[cc][r] = fmaf(cv, xi, -sv * xr);
        }
        wht10_s(vr[cc], lane);
        wht10_s(vi[cc], lane);
    }

    // ---- registers -> LDS (own words only; no pre-barrier needed) ----
    #pragma unroll
    for (int r = 0; r < 16; r++) {
        int h = r * 64 + lane;
        int e = (lane >> 2) & 7;
        int wp = w ^ e;
        union { float f; __half2 h2; } ur, ui;
        ur.h2 = __float22half2_rn(make_float2(vr[0][r] * 0.03125f, vr[1][r] * 0.03125f));
        ui.h2 = __float22half2_rn(make_float2(vi[0][r] * 0.03125f, vi[1][r] * 0.03125f));
        tile[0][h][wp] = ur.f;
        tile[1][h][wp] = ui.f;
    }
    __syncthreads();

    // ---- stage-out: swizzled LDS -> coalesced global ----
    #pragma unroll
    for (int comp = 0; comp < 2; comp++) {
        __half* dstg = comp ? baseI : baseR;
        #pragma unroll
        for (int it = 0; it < 4; it++) {
            int f = it * 512 + tid;
            int h = f >> 1, q = f & 1;
            int e = (h >> 2) & 7;
            int elo = e & 3;
            int qp = q ^ (e >> 2);
            float4 sv = *(const float4*)&tile[comp][h][qp * 4];
            bool s0 = (elo & 1) != 0;
            float x1 = s0 ? sv.y : sv.x, y1 = s0 ? sv.x : sv.y;
            float z1 = s0 ? sv.w : sv.z, w1 = s0 ? sv.z : sv.w;
            bool s1 = (elo & 2) != 0;
            float x2 = s1 ? z1 : x1, y2 = s1 ? w1 : y1;
            float z2 = s1 ? x1 : z1, w2 = s1 ? y1 : w1;
            *(float4*)(dstg + (size_t)h * 1024 + c0 + q * 8) = make_float4(x2, y2, z2, w2);
        }
    }
}

// ============================ fp32 fallback (R1 kernels) ============================

__global__ __launch_bounds__(256) void pass13_kernel(const float* __restrict__ srcA,
                                                     const float* __restrict__ srcB,
                                                     float* __restrict__ dst) {
    const int tid  = threadIdx.x;
    const int lane = tid & 63;
    const int w    = tid >> 6;
    const int rt0  = blockIdx.x * 16 + w * 4;
    const float* src = (rt0 < 16384) ? (srcA + (size_t)rt0 * 1024)
                                     : (srcB + (size_t)(rt0 - 16384) * 1024);
    float* d = dst + (size_t)rt0 * 1024;

    float4 v[4][4];
    #pragma unroll
    for (int rr = 0; rr < 4; rr++)
        #pragma unroll
        for (int r = 0; r < 4; r++)
            v[rr][r] = *(const float4*)(src + rr * 1024 + r * 256 + lane * 4);

    #pragma unroll
    for (int rr = 0; rr < 4; rr++) {
        wht10_f4(v[rr], lane);
        #pragma unroll
        for (int r = 0; r < 4; r++) {
            float4 o;
            o.x = v[rr][r].x * 0.03125f;
            o.y = v[rr][r].y * 0.03125f;
            o.z = v[rr][r].z * 0.03125f;
            o.w = v[rr][r].w * 0.03125f;
            *(float4*)(d + rr * 1024 + r * 256 + lane * 4) = o;
        }
    }
}

__global__ __launch_bounds__(256) void pass2_kernel(float* __restrict__ out,
                                                    const float* __restrict__ tptr) {
    __shared__ __align__(16) float tile[2][1024][8];
    const int tid  = threadIdx.x;
    const int lane = tid & 63;
    const int w    = tid >> 6;

    int wg  = blockIdx.x;
    int swz = (wg & 7) * 256 + (wg >> 3);
    const int b  = swz >> 7;
    const int g  = swz & 127;
    const int c0 = g * 8;
    const float tval = tptr[0];

    float* baseR = out + (size_t)b * DIMN;
    float* baseI = out + (size_t)16 * DIMN + (size_t)b * DIMN;

    float4 tmp[2][8];
    #pragma unroll
    for (int comp = 0; comp < 2; comp++) {
        const float* src = comp ? baseI : baseR;
        #pragma unroll
        for (int it = 0; it < 8; it++) {
            int f4id = it * 256 + tid;
            int h = f4id >> 1, q = f4id & 1;
            tmp[comp][it] = *(const float4*)(src + (size_t)h * 1024 + c0 + q * 4);
        }
    }
    #pragma unroll
    for (int comp = 0; comp < 2; comp++) {
        #pragma unroll
        for (int it = 0; it < 8; it++) {
            int f4id = it * 256 + tid;
            int h = f4id >> 1, q = f4id & 1;
            int e = (h >> 2) & 7;
            int elo = e & 3;
            float4 val = tmp[comp][it];
            bool s0 = (elo & 1) != 0;
            float x1 = s0 ? val.y : val.x, y1 = s0 ? val.x : val.y;
            float z1 = s0 ? val.w : val.z, w1 = s0 ? val.z : val.w;
            bool s1 = (elo & 2) != 0;
            float x2 = s1 ? z1 : x1, y2 = s1 ? w1 : y1;
            float z2 = s1 ? x1 : z1, w2 = s1 ? y1 : w1;
            int qp = q ^ (e >> 2);
            *(float4*)&tile[comp][h][qp * 4] = make_float4(x2, y2, z2, w2);
        }
    }
    __syncthreads();

    float vr[2][16], vi[2][16];
    #pragma unroll
    for (int r = 0; r < 16; r++) {
        int h = r * 64 + lane;
        int e = (lane >> 2) & 7;
        #pragma unroll
        for (int cc = 0; cc < 2; cc++) {
            int cp = (2 * w + cc) ^ e;
            vr[cc][r] = tile[0][h][cp];
            vi[cc][r] = tile[1][h][cp];
        }
    }

    const int pcl = __popc(lane);
    #pragma unroll
    for (int cc = 0; cc < 2; cc++) {
        wht10_s(vr[cc], lane);
        wht10_s(vi[cc], lane);
        const int cg = c0 + 2 * w + cc;
        const int pbase = pcl + __popc(cg);
        float csk[5], snk[5];
        #pragma unroll
        for (int k = 0; k < 5; k++) {
            float ang = tval * (float)(20 - 2 * (pbase + k));
            sincosf(ang, &snk[k], &csk[k]);
        }
        #pragma unroll
        for (int r = 0; r < 16; r++) {
            const int pr = __popc(r);
            float cv = csk[pr], sv = snk[pr];
            float xr = vr[cc][r] * 0.03125f;
            float xi = vi[cc][r] * 0.03125f;
            vr[cc][r] = fmaf(cv, xr, sv * xi);
            vi[cc][r] = fmaf(cv, xi, -sv * xr);
        }
        wht10_s(vr[cc], lane);
        wht10_s(vi[cc], lane);
    }

    #pragma unroll
    for (int r = 0; r < 16; r++) {
        int h = r * 64 + lane;
        int e = (lane >> 2) & 7;
        #pragma unroll
        for (int cc = 0; cc < 2; cc++) {
            int cp = (2 * w + cc) ^ e;
            tile[0][h][cp] = vr[cc][r] * 0.03125f;
            tile[1][h][cp] = vi[cc][r] * 0.03125f;
        }
    }
    __syncthreads();

    #pragma unroll
    for (int comp = 0; comp < 2; comp++) {
        float* dstg = comp ? baseI : baseR;
        #pragma unroll
        for (int it = 0; it < 8; it++) {
            int f4id = it * 256 + tid;
            int h = f4id >> 1, q = f4id & 1;
            int e = (h >> 2) & 7;
            int elo = e & 3;
            int qp = q ^ (e >> 2);
            float4 sv = *(const float4*)&tile[comp][h][qp * 4];
            bool s0 = (elo & 1) != 0;
            float x1 = s0 ? sv.y : sv.x, y1 = s0 ? sv.x : sv.y;
            float z1 = s0 ? sv.w : sv.z, w1 = s0 ? sv.z : sv.w;
            bool s1 = (elo & 2) != 0;
            float x2 = s1 ? z1 : x1, y2 = s1 ? w1 : y1;
            float z2 = s1 ? x1 : z1, w2 = s1 ? y1 : w1;
            *(float4*)(dstg + (size_t)h * 1024 + c0 + q * 4) = make_float4(x2, y2, z2, w2);
        }
    }
}

extern "C" void kernel_launch(void* const* d_in, const int* in_sizes, int n_in,
                              void* d_out, int out_size, void* d_ws, size_t ws_size,
                              hipStream_t stream) {
    const float* xr = (const float*)d_in[0];
    const float* xi = (const float*)d_in[1];
    const float* t  = (const float*)d_in[2];
    float* out = (float*)d_out;

    const size_t need = (size_t)2 * 16 * DIMN * sizeof(__half);  // 64 MiB
    if (ws_size >= need) {
        __half* ws = (__half*)d_ws;
        pass1_h_kernel<<<2048, 256, 0, stream>>>(xr, xi, ws);
        pass2_h_kernel<<<1024, 512, 0, stream>>>(ws, t);
        pass3_h_kernel<<<2048, 256, 0, stream>>>(ws, out);
    } else {
        pass13_kernel<<<2048, 256, 0, stream>>>(xr, xi, out);
        pass2_kernel<<<2048, 256, 0, stream>>>(out, t);
        pass13_kernel<<<2048, 256, 0, stream>>>(out, out + (size_t)16 * DIMN, out);
    }
}

// Round 3
// 134.798 us; speedup vs baseline: 1.3298x; 1.3298x over previous
//
#include <hip/hip_runtime.h>
#include <hip/hip_fp16.h>
#include <math.h>

#define DIMN (1 << 20)   // 2^20 per batch row
// d_out: [2][16][DIMN] f32.  d_ws (fp16 path): [2][16][DIMN] __half.

// ---------------- bit-cast helpers ----------------
__device__ __forceinline__ unsigned int h2u(__half2 v){ union{__half2 h; unsigned int u;} x; x.h=v; return x.u; }
__device__ __forceinline__ __half2 u2h(unsigned int v){ union{unsigned int u; __half2 h;} x; x.u=v; return x.h; }
__device__ __forceinline__ float h2fl(__half2 v){ union{__half2 h; float f;} x; x.h=v; return x.f; }
__device__ __forceinline__ __half2 fl2h(float v){ union{float f; __half2 h;} x; x.f=v; return x.h; }

__device__ __forceinline__ void bf(float& a, float& b) { float s = a + b; b = a - b; a = s; }

// ---------------- f32 WHT over 10 bits, layout l = q*256 + lane*4 + s ----------------
// reg bits {0,1,8,9} (r = q*4+s pairing 1,2,4,8), lane bits {2..7} (masks 1..32)
__device__ __forceinline__ void wht16_f32(float v[16], int lane) {
    #pragma unroll
    for (int s = 1; s < 16; s <<= 1)
        #pragma unroll
        for (int r = 0; r < 16; r++)
            if (!(r & s)) bf(v[r], v[r ^ s]);
    #pragma unroll
    for (int m = 1; m <= 32; m <<= 1) {
        float sgn = (lane & m) ? -1.0f : 1.0f;
        #pragma unroll
        for (int r = 0; r < 16; r++) {
            float p = __shfl_xor(v[r], m);
            v[r] = fmaf(sgn, v[r], p);
        }
    }
}

// ---------------- half2 (re,im)-packed WHT over 10 bits, layout h = r*64 + lane ----------------
__device__ __forceinline__ void wht16_h2(__half2 v[16], int lane) {
    #pragma unroll
    for (int s = 1; s < 16; s <<= 1)
        #pragma unroll
        for (int r = 0; r < 16; r++)
            if (!(r & s)) {
                __half2 t = __hadd2(v[r], v[r ^ s]);
                v[r ^ s]  = __hsub2(v[r], v[r ^ s]);
                v[r] = t;
            }
    #pragma unroll
    for (int m = 1; m <= 32; m <<= 1) {
        __half2 sgn = __float2half2_rn((lane & m) ? -1.0f : 1.0f);
        #pragma unroll
        for (int r = 0; r < 16; r++) {
            float pv = __shfl_xor(h2fl(v[r]), m);
            v[r] = __hfma2(v[r], sgn, fl2h(pv));
        }
    }
}

// XOR-permute 4 words by elo (0..3), compile-time indices only
__device__ __forceinline__ void xorperm4(unsigned int a[4], int elo) {
    bool s0 = (elo & 1) != 0, s1 = (elo & 2) != 0;
    unsigned int t0 = s0 ? a[1] : a[0], t1 = s0 ? a[0] : a[1];
    unsigned int t2 = s0 ? a[3] : a[2], t3 = s0 ? a[2] : a[3];
    a[0] = s1 ? t2 : t0; a[1] = s1 ? t3 : t1;
    a[2] = s1 ? t0 : t2; a[3] = s1 ? t1 : t3;
}

// ================= Pass 1: f32 in -> low-10 WHT (f32 math) -> fp16 ws =================
__global__ __launch_bounds__(256, 4) void p1_kernel(const float* __restrict__ xr,
                                                    const float* __restrict__ xi,
                                                    __half* __restrict__ ws) {
    const int tid = threadIdx.x, lane = tid & 63, w = tid >> 6;
    const int rt = blockIdx.x * 4 + w;              // (batch*1024 + h) in [0,16384)
    const float* re = xr + (size_t)rt * 1024;
    const float* im = xi + (size_t)rt * 1024;
    float vr[16], vi[16];
    #pragma unroll
    for (int q = 0; q < 4; q++) {
        float4 a = *(const float4*)(re + q * 256 + lane * 4);
        float4 b = *(const float4*)(im + q * 256 + lane * 4);
        vr[q*4+0] = a.x * 0.03125f; vr[q*4+1] = a.y * 0.03125f;
        vr[q*4+2] = a.z * 0.03125f; vr[q*4+3] = a.w * 0.03125f;
        vi[q*4+0] = b.x * 0.03125f; vi[q*4+1] = b.y * 0.03125f;
        vi[q*4+2] = b.z * 0.03125f; vi[q*4+3] = b.w * 0.03125f;
    }
    wht16_f32(vr, lane);
    wht16_f32(vi, lane);
    __half* wr = ws + (size_t)rt * 1024;
    __half* wi = ws + (size_t)16 * DIMN + (size_t)rt * 1024;
    #pragma unroll
    for (int q = 0; q < 4; q++) {
        uint2 pr = make_uint2(h2u(__floats2half2_rn(vr[q*4+0], vr[q*4+1])),
                              h2u(__floats2half2_rn(vr[q*4+2], vr[q*4+3])));
        uint2 pi = make_uint2(h2u(__floats2half2_rn(vi[q*4+0], vi[q*4+1])),
                              h2u(__floats2half2_rn(vi[q*4+2], vi[q*4+3])));
        *(uint2*)(wr + q * 256 + lane * 4) = pr;
        *(uint2*)(wi + q * 256 + lane * 4) = pi;
    }
}

// ================= Pass 3: fp16 ws -> low-10 WHT (f32 math) -> f32 out =================
__global__ __launch_bounds__(256, 4) void p3_kernel(const __half* __restrict__ ws,
                                                    float* __restrict__ out) {
    const int tid = threadIdx.x, lane = tid & 63, w = tid >> 6;
    const int rt = blockIdx.x * 4 + w;
    const __half* wr = ws + (size_t)rt * 1024;
    const __half* wi = ws + (size_t)16 * DIMN + (size_t)rt * 1024;
    float vr[16], vi[16];
    #pragma unroll
    for (int q = 0; q < 4; q++) {
        uint2 pr = *(const uint2*)(wr + q * 256 + lane * 4);
        uint2 pi = *(const uint2*)(wi + q * 256 + lane * 4);
        __half2 a0 = u2h(pr.x), a1 = u2h(pr.y), b0 = u2h(pi.x), b1 = u2h(pi.y);
        vr[q*4+0] = __low2float(a0) * 0.03125f; vr[q*4+1] = __high2float(a0) * 0.03125f;
        vr[q*4+2] = __low2float(a1) * 0.03125f; vr[q*4+3] = __high2float(a1) * 0.03125f;
        vi[q*4+0] = __low2float(b0) * 0.03125f; vi[q*4+1] = __high2float(b0) * 0.03125f;
        vi[q*4+2] = __low2float(b1) * 0.03125f; vi[q*4+3] = __high2float(b1) * 0.03125f;
    }
    wht16_f32(vr, lane);
    wht16_f32(vi, lane);
    float* outr = out + (size_t)rt * 1024;
    float* outi = out + (size_t)16 * DIMN + (size_t)rt * 1024;
    #pragma unroll
    for (int q = 0; q < 4; q++) {
        *(float4*)(outr + q * 256 + lane * 4) = make_float4(vr[q*4+0], vr[q*4+1], vr[q*4+2], vr[q*4+3]);
        *(float4*)(outi + q * 256 + lane * 4) = make_float4(vi[q*4+0], vi[q*4+1], vi[q*4+2], vi[q*4+3]);
    }
}

// ================= Pass 2: high-10 WHT + rotate + high-10 WHT, half2(re,im) packed =================
// Tile: [1024 h][8 cols] of half2 = 32 KiB LDS. 512 threads, wave w owns column w.
__global__ __launch_bounds__(512, 4) void p2_kernel(__half* __restrict__ ws,
                                                    const float* __restrict__ tptr) {
    __shared__ unsigned int tile[1024][8];
    const int tid = threadIdx.x, lane = tid & 63, w = tid >> 6;

    // XCD-chunked bijective swizzle (2048 % 8 == 0)
    int wg  = blockIdx.x;
    int swz = (wg & 7) * 256 + (wg >> 3);
    const int b  = swz >> 7;           // batch 0..15
    const int g  = swz & 127;          // column group 0..127
    const int c0 = g * 8;
    const float tval = tptr[0];

    __half* re = ws + (size_t)b * DIMN + c0;
    __half* im = ws + (size_t)16 * DIMN + (size_t)b * DIMN + c0;

    // ---- stage-in: interleave (re,im) -> half2 words, swizzled LDS ----
    #pragma unroll
    for (int it = 0; it < 2; it++) {
        int h = it * 512 + tid;
        uint4 ra = *(const uint4*)(re + (size_t)h * 1024);
        uint4 ia = *(const uint4*)(im + (size_t)h * 1024);
        unsigned int g0[4], g1[4];
        g0[0] = (ra.x & 0xFFFFu) | (ia.x << 16);
        g0[1] = (ra.x >> 16)     | (ia.x & 0xFFFF0000u);
        g0[2] = (ra.y & 0xFFFFu) | (ia.y << 16);
        g0[3] = (ra.y >> 16)     | (ia.y & 0xFFFF0000u);
        g1[0] = (ra.z & 0xFFFFu) | (ia.z << 16);
        g1[1] = (ra.z >> 16)     | (ia.z & 0xFFFF0000u);
        g1[2] = (ra.w & 0xFFFFu) | (ia.w << 16);
        g1[3] = (ra.w >> 16)     | (ia.w & 0xFFFF0000u);
        int e = (h >> 2) & 7;
        xorperm4(g0, e & 3);
        xorperm4(g1, e & 3);
        int ehi = (e >> 2) & 1;
        *(uint4*)&tile[h][ehi ? 4 : 0] = make_uint4(g0[0], g0[1], g0[2], g0[3]);
        *(uint4*)&tile[h][ehi ? 0 : 4] = make_uint4(g1[0], g1[1], g1[2], g1[3]);
    }
    __syncthreads();

    // ---- LDS -> regs: wave w's logical column w (conflict-free: bank = (lane&3)*8 + (w^e)) ----
    const int ecol = w ^ ((lane >> 2) & 7);   // e(h) = (lane>>2)&7 since h = r*64+lane
    const __half2 sc = __float2half2_rn(0.03125f);
    __half2 v[16];
    #pragma unroll
    for (int r = 0; r < 16; r++)
        v[r] = __hmul2(u2h(tile[r * 64 + lane][ecol]), sc);   // pre-scale 2^-5

    // ---- WHT #1 (high 10 bits) ----
    wht16_h2(v, lane);

    // ---- rotation (f32 per element), fold 2^-5 pre-scale for WHT #2 into cs/sn ----
    const int l = c0 + w;
    const int pbase = __popc(lane) + __popc(l);
    float cs[5], sn[5];
    #pragma unroll
    for (int k = 0; k < 5; k++) {
        float ang = tval * (float)(20 - 2 * (pbase + k));
        float s, c;
        sincosf(ang, &s, &c);
        cs[k] = c * 0.03125f;
        sn[k] = s * 0.03125f;
    }
    #pragma unroll
    for (int r = 0; r < 16; r++) {
        const int pr = __popc(r);             // compile-time (r unrolled), 0..4
        float xr = __low2float(v[r]), xi = __high2float(v[r]);
        float yr = cs[pr] * xr + sn[pr] * xi;
        float yi = cs[pr] * xi - sn[pr] * xr;
        v[r] = __floats2half2_rn(yr, yi);
    }

    // ---- WHT #2 (high 10 bits) ----
    wht16_h2(v, lane);

    // ---- regs -> LDS (own column) ----
    #pragma unroll
    for (int r = 0; r < 16; r++)
        tile[r * 64 + lane][ecol] = h2u(v[r]);
    __syncthreads();

    // ---- stage-out: inverse of stage-in ----
    #pragma unroll
    for (int it = 0; it < 2; it++) {
        int h = it * 512 + tid;
        int e = (h >> 2) & 7;
        int ehi = (e >> 2) & 1;
        uint4 u0 = *(const uint4*)&tile[h][ehi ? 4 : 0];
        uint4 u1 = *(const uint4*)&tile[h][ehi ? 0 : 4];
        unsigned int g0[4] = {u0.x, u0.y, u0.z, u0.w};
        unsigned int g1[4] = {u1.x, u1.y, u1.z, u1.w};
        xorperm4(g0, e & 3);
        xorperm4(g1, e & 3);
        uint4 ra, ia;
        ra.x = (g0[0] & 0xFFFFu) | (g0[1] << 16);
        ia.x = (g0[0] >> 16)     | (g0[1] & 0xFFFF0000u);
        ra.y = (g0[2] & 0xFFFFu) | (g0[3] << 16);
        ia.y = (g0[2] >> 16)     | (g0[3] & 0xFFFF0000u);
        ra.z = (g1[0] & 0xFFFFu) | (g1[1] << 16);
        ia.z = (g1[0] >> 16)     | (g1[1] & 0xFFFF0000u);
        ra.w = (g1[2] & 0xFFFFu) | (g1[3] << 16);
        ia.w = (g1[2] >> 16)     | (g1[3] & 0xFFFF0000u);
        *(uint4*)(re + (size_t)h * 1024) = ra;
        *(uint4*)(im + (size_t)h * 1024) = ia;
    }
}

// ================= fp32 fallback (R1 kernels, proven) =================
__device__ __forceinline__ void wht10_f4(float4 v[4], int lane) {
    #pragma unroll
    for (int r = 0; r < 4; r++) {
        bf(v[r].x, v[r].y); bf(v[r].z, v[r].w);
        bf(v[r].x, v[r].z); bf(v[r].y, v[r].w);
    }
    #pragma unroll
    for (int m = 1; m <= 32; m <<= 1) {
        float sgn = (lane & m) ? -1.0f : 1.0f;
        #pragma unroll
        for (int r = 0; r < 4; r++) {
            float px = __shfl_xor(v[r].x, m), py = __shfl_xor(v[r].y, m);
            float pz = __shfl_xor(v[r].z, m), pw = __shfl_xor(v[r].w, m);
            v[r].x = fmaf(sgn, v[r].x, px); v[r].y = fmaf(sgn, v[r].y, py);
            v[r].z = fmaf(sgn, v[r].z, pz); v[r].w = fmaf(sgn, v[r].w, pw);
        }
    }
    #pragma unroll
    for (int r = 0; r < 4; r++) { }
    { float s;
      s = v[0].x + v[1].x; v[1].x = v[0].x - v[1].x; v[0].x = s;
      s = v[0].y + v[1].y; v[1].y = v[0].y - v[1].y; v[0].y = s;
      s = v[0].z + v[1].z; v[1].z = v[0].z - v[1].z; v[0].z = s;
      s = v[0].w + v[1].w; v[1].w = v[0].w - v[1].w; v[0].w = s;
      s = v[2].x + v[3].x; v[3].x = v[2].x - v[3].x; v[2].x = s;
      s = v[2].y + v[3].y; v[3].y = v[2].y - v[3].y; v[2].y = s;
      s = v[2].z + v[3].z; v[3].z = v[2].z - v[3].z; v[2].z = s;
      s = v[2].w + v[3].w; v[3].w = v[2].w - v[3].w; v[2].w = s;
      s = v[0].x + v[2].x; v[2].x = v[0].x - v[2].x; v[0].x = s;
      s = v[0].y + v[2].y; v[2].y = v[0].y - v[2].y; v[0].y = s;
      s = v[0].z + v[2].z; v[2].z = v[0].z - v[2].z; v[0].z = s;
      s = v[0].w + v[2].w; v[2].w = v[0].w - v[2].w; v[0].w = s;
      s = v[1].x + v[3].x; v[3].x = v[1].x - v[3].x; v[1].x = s;
      s = v[1].y + v[3].y; v[3].y = v[1].y - v[3].y; v[1].y = s;
      s = v[1].z + v[3].z; v[3].z = v[1].z - v[3].z; v[1].z = s;
      s = v[1].w + v[3].w; v[3].w = v[1].w - v[3].w; v[1].w = s; }
}

__global__ __launch_bounds__(256) void pass13_kernel(const float* __restrict__ srcA,
                                                     const float* __restrict__ srcB,
                                                     float* __restrict__ dst) {
    const int tid = threadIdx.x, lane = tid & 63, w = tid >> 6;
    const int rt0 = blockIdx.x * 16 + w * 4;
    const float* src = (rt0 < 16384) ? (srcA + (size_t)rt0 * 1024)
                                     : (srcB + (size_t)(rt0 - 16384) * 1024);
    float* d = dst + (size_t)rt0 * 1024;
    float4 v[4][4];
    #pragma unroll
    for (int rr = 0; rr < 4; rr++)
        #pragma unroll
        for (int r = 0; r < 4; r++)
            v[rr][r] = *(const float4*)(src + rr * 1024 + r * 256 + lane * 4);
    #pragma unroll
    for (int rr = 0; rr < 4; rr++) {
        wht10_f4(v[rr], lane);
        #pragma unroll
        for (int r = 0; r < 4; r++) {
            float4 o;
            o.x = v[rr][r].x * 0.03125f; o.y = v[rr][r].y * 0.03125f;
            o.z = v[rr][r].z * 0.03125f; o.w = v[rr][r].w * 0.03125f;
            *(float4*)(d + rr * 1024 + r * 256 + lane * 4) = o;
        }
    }
}

__global__ __launch_bounds__(256) void pass2_kernel(float* __restrict__ out,
                                                    const float* __restrict__ tptr) {
    __shared__ __align__(16) float tile[2][1024][8];
    const int tid = threadIdx.x, lane = tid & 63, w = tid >> 6;
    int wg = blockIdx.x;
    int swz = (wg & 7) * 256 + (wg >> 3);
    const int b = swz >> 7, g = swz & 127;
    const int c0 = g * 8;
    const float tval = tptr[0];
    float* baseR = out + (size_t)b * DIMN;
    float* baseI = out + (size_t)16 * DIMN + (size_t)b * DIMN;
    float4 tmp[2][8];
    #pragma unroll
    for (int comp = 0; comp < 2; comp++) {
        const float* src = comp ? baseI : baseR;
        #pragma unroll
        for (int it = 0; it < 8; it++) {
            int f4id = it * 256 + tid;
            int h = f4id >> 1, q = f4id & 1;
            tmp[comp][it] = *(const float4*)(src + (size_t)h * 1024 + c0 + q * 4);
        }
    }
    #pragma unroll
    for (int comp = 0; comp < 2; comp++) {
        #pragma unroll
        for (int it = 0; it < 8; it++) {
            int f4id = it * 256 + tid;
            int h = f4id >> 1, q = f4id & 1;
            int e = (h >> 2) & 7, elo = e & 3;
            float4 val = tmp[comp][it];
            bool s0 = (elo & 1) != 0;
            float x1 = s0 ? val.y : val.x, y1 = s0 ? val.x : val.y;
            float z1 = s0 ? val.w : val.z, w1 = s0 ? val.z : val.w;
            bool s1 = (elo & 2) != 0;
            float x2 = s1 ? z1 : x1, y2 = s1 ? w1 : y1;
            float z2 = s1 ? x1 : z1, w2 = s1 ? y1 : w1;
            int qp = q ^ (e >> 2);
            *(float4*)&tile[comp][h][qp * 4] = make_float4(x2, y2, z2, w2);
        }
    }
    __syncthreads();
    float vr[2][16], vi[2][16];
    #pragma unroll
    for (int r = 0; r < 16; r++) {
        int h = r * 64 + lane;
        int e = (lane >> 2) & 7;
        #pragma unroll
        for (int cc = 0; cc < 2; cc++) {
            int cp = (2 * w + cc) ^ e;
            vr[cc][r] = tile[0][h][cp];
            vi[cc][r] = tile[1][h][cp];
        }
    }
    const int pcl = __popc(lane);
    #pragma unroll
    for (int cc = 0; cc < 2; cc++) {
        float* pr2 = vr[cc];
        float* pi2 = vi[cc];
        #pragma unroll
        for (int m = 1; m <= 32; m <<= 1) {
            float sgn = (lane & m) ? -1.0f : 1.0f;
            #pragma unroll
            for (int r = 0; r < 16; r++) {
                float p = __shfl_xor(pr2[r], m); pr2[r] = fmaf(sgn, pr2[r], p);
                float q = __shfl_xor(pi2[r], m); pi2[r] = fmaf(sgn, pi2[r], q);
            }
        }
        #pragma unroll
        for (int s = 1; s < 16; s <<= 1)
            #pragma unroll
            for (int r = 0; r < 16; r++)
                if (!(r & s)) { bf(pr2[r], pr2[r ^ s]); bf(pi2[r], pi2[r ^ s]); }
        const int cg = c0 + 2 * w + cc;
        const int pbase = pcl + __popc(cg);
        float csk[5], snk[5];
        #pragma unroll
        for (int k = 0; k < 5; k++) {
            float ang = tval * (float)(20 - 2 * (pbase + k));
            sincosf(ang, &snk[k], &csk[k]);
        }
        #pragma unroll
        for (int r = 0; r < 16; r++) {
            const int pr = __popc(r);
            float cv = csk[pr], sv = snk[pr];
            float xr = pr2[r] * 0.03125f, xi = pi2[r] * 0.03125f;
            pr2[r] = fmaf(cv, xr, sv * xi);
            pi2[r] = fmaf(cv, xi, -sv * xr);
        }
        #pragma unroll
        for (int m = 1; m <= 32; m <<= 1) {
            float sgn = (lane & m) ? -1.0f : 1.0f;
            #pragma unroll
            for (int r = 0; r < 16; r++) {
                float p = __shfl_xor(pr2[r], m); pr2[r] = fmaf(sgn, pr2[r], p);
                float q = __shfl_xor(pi2[r], m); pi2[r] = fmaf(sgn, pi2[r], q);
            }
        }
        #pragma unroll
        for (int s = 1; s < 16; s <<= 1)
            #pragma unroll
            for (int r = 0; r < 16; r++)
                if (!(r & s)) { bf(pr2[r], pr2[r ^ s]); bf(pi2[r], pi2[r ^ s]); }
    }
    #pragma unroll
    for (int r = 0; r < 16; r++) {
        int h = r * 64 + lane;
        int e = (lane >> 2) & 7;
        #pragma unroll
        for (int cc = 0; cc < 2; cc++) {
            int cp = (2 * w + cc) ^ e;
            tile[0][h][cp] = vr[cc][r] * 0.03125f;
            tile[1][h][cp] = vi[cc][r] * 0.03125f;
        }
    }
    __syncthreads();
    #pragma unroll
    for (int comp = 0; comp < 2; comp++) {
        float* dstg = comp ? baseI : baseR;
        #pragma unroll
        for (int it = 0; it < 8; it++) {
            int f4id = it * 256 + tid;
            int h = f4id >> 1, q = f4id & 1;
            int e = (h >> 2) & 7, elo = e & 3;
            int qp = q ^ (e >> 2);
            float4 sv = *(const float4*)&tile[comp][h][qp * 4];
            bool s0 = (elo & 1) != 0;
            float x1 = s0 ? sv.y : sv.x, y1 = s0 ? sv.x : sv.y;
            float z1 = s0 ? sv.w : sv.z, w1 = s0 ? sv.z : sv.w;
            bool s1 = (elo & 2) != 0;
            float x2 = s1 ? z1 : x1, y2 = s1 ? w1 : y1;
            float z2 = s1 ? x1 : z1, w2 = s1 ? y1 : w1;
            *(float4*)(dstg + (size_t)h * 1024 + c0 + q * 4) = make_float4(x2, y2, z2, w2);
        }
    }
}

extern "C" void kernel_launch(void* const* d_in, const int* in_sizes, int n_in,
                              void* d_out, int out_size, void* d_ws, size_t ws_size,
                              hipStream_t stream) {
    const float* xr = (const float*)d_in[0];
    const float* xi = (const float*)d_in[1];
    const float* t  = (const float*)d_in[2];
    float* out = (float*)d_out;

    const size_t need = (size_t)2 * 16 * DIMN * sizeof(__half);  // 64 MiB
    if (ws_size >= need) {
        __half* ws = (__half*)d_ws;
        p1_kernel<<<4096, 256, 0, stream>>>(xr, xi, ws);
        p2_kernel<<<2048, 512, 0, stream>>>(ws, t);
        p3_kernel<<<4096, 256, 0, stream>>>(ws, out);
    } else {
        pass13_kernel<<<2048, 256, 0, stream>>>(xr, xi, out);
        pass2_kernel<<<2048, 256, 0, stream>>>(out, t);
        pass13_kernel<<<2048, 256, 0, stream>>>(out, out + (size_t)16 * DIMN, out);
    }
}

// Round 4
// 121.278 us; speedup vs baseline: 1.4781x; 1.1115x over previous
//
#include <hip/hip_runtime.h>
#include <hip/hip_fp16.h>
#include <math.h>

#define DIMN (1 << 20)   // 2^20 per batch row
// d_out: [2][16][DIMN] f32.  d_ws (fp16 path): [2][16][DIMN] __half.

// ---------------- bit-cast helpers ----------------
__device__ __forceinline__ unsigned int h2u(__half2 v){ union{__half2 h; unsigned int u;} x; x.h=v; return x.u; }
__device__ __forceinline__ __half2 u2h(unsigned int v){ union{unsigned int u; __half2 h;} x; x.u=v; return x.h; }

__device__ __forceinline__ void bf(float& a, float& b) { float s = a + b; b = a - b; a = s; }

// ---------------- DPP lane-exchange (VALU pipe, not DS) ----------------
// xor1 = quad_perm[1,0,3,2] = 0xB1 ; xor2 = quad_perm[2,3,0,1] = 0x4E ;
// xor8 = row_ror:8 = 0x128 (rotate by 8 within 16-lane row == lane^8)
template<int CTRL>
__device__ __forceinline__ float dppf(float x) {
    return __int_as_float(__builtin_amdgcn_mov_dpp(__float_as_int(x), CTRL, 0xF, 0xF, true));
}
template<int CTRL>
__device__ __forceinline__ unsigned int dppu(unsigned int x) {
    return (unsigned int)__builtin_amdgcn_mov_dpp((int)x, CTRL, 0xF, 0xF, true);
}

// ---------------- f32 WHT over 10 bits ----------------
// reg bits (pairing 1,2,4,8) + 6 lane bits (masks 1..32)
__device__ __forceinline__ void wht16_f32(float v[16], int lane) {
    #pragma unroll
    for (int s = 1; s < 16; s <<= 1)
        #pragma unroll
        for (int r = 0; r < 16; r++)
            if (!(r & s)) bf(v[r], v[r ^ s]);
    {   float sgn = (lane & 1) ? -1.0f : 1.0f;
        #pragma unroll
        for (int r = 0; r < 16; r++) { float p = dppf<0xB1>(v[r]); v[r] = fmaf(sgn, v[r], p); } }
    {   float sgn = (lane & 2) ? -1.0f : 1.0f;
        #pragma unroll
        for (int r = 0; r < 16; r++) { float p = dppf<0x4E>(v[r]); v[r] = fmaf(sgn, v[r], p); } }
    {   float sgn = (lane & 4) ? -1.0f : 1.0f;
        #pragma unroll
        for (int r = 0; r < 16; r++) { float p = __shfl_xor(v[r], 4); v[r] = fmaf(sgn, v[r], p); } }
    {   float sgn = (lane & 8) ? -1.0f : 1.0f;
        #pragma unroll
        for (int r = 0; r < 16; r++) { float p = dppf<0x128>(v[r]); v[r] = fmaf(sgn, v[r], p); } }
    {   float sgn = (lane & 16) ? -1.0f : 1.0f;
        #pragma unroll
        for (int r = 0; r < 16; r++) { float p = __shfl_xor(v[r], 16); v[r] = fmaf(sgn, v[r], p); } }
    {   float sgn = (lane & 32) ? -1.0f : 1.0f;
        #pragma unroll
        for (int r = 0; r < 16; r++) { float p = __shfl_xor(v[r], 32); v[r] = fmaf(sgn, v[r], p); } }
}

// ---------------- half2 (re,im)-packed WHT over 10 bits ----------------
__device__ __forceinline__ void wht16_h2(__half2 v[16], int lane) {
    #pragma unroll
    for (int s = 1; s < 16; s <<= 1)
        #pragma unroll
        for (int r = 0; r < 16; r++)
            if (!(r & s)) {
                __half2 t = __hadd2(v[r], v[r ^ s]);
                v[r ^ s]  = __hsub2(v[r], v[r ^ s]);
                v[r] = t;
            }
    {   __half2 sgn = __float2half2_rn((lane & 1) ? -1.0f : 1.0f);
        #pragma unroll
        for (int r = 0; r < 16; r++) { __half2 p = u2h(dppu<0xB1>(h2u(v[r]))); v[r] = __hfma2(v[r], sgn, p); } }
    {   __half2 sgn = __float2half2_rn((lane & 2) ? -1.0f : 1.0f);
        #pragma unroll
        for (int r = 0; r < 16; r++) { __half2 p = u2h(dppu<0x4E>(h2u(v[r]))); v[r] = __hfma2(v[r], sgn, p); } }
    {   __half2 sgn = __float2half2_rn((lane & 4) ? -1.0f : 1.0f);
        #pragma unroll
        for (int r = 0; r < 16; r++) { __half2 p = u2h((unsigned)__shfl_xor((int)h2u(v[r]), 4)); v[r] = __hfma2(v[r], sgn, p); } }
    {   __half2 sgn = __float2half2_rn((lane & 8) ? -1.0f : 1.0f);
        #pragma unroll
        for (int r = 0; r < 16; r++) { __half2 p = u2h(dppu<0x128>(h2u(v[r]))); v[r] = __hfma2(v[r], sgn, p); } }
    {   __half2 sgn = __float2half2_rn((lane & 16) ? -1.0f : 1.0f);
        #pragma unroll
        for (int r = 0; r < 16; r++) { __half2 p = u2h((unsigned)__shfl_xor((int)h2u(v[r]), 16)); v[r] = __hfma2(v[r], sgn, p); } }
    {   __half2 sgn = __float2half2_rn((lane & 32) ? -1.0f : 1.0f);
        #pragma unroll
        for (int r = 0; r < 16; r++) { __half2 p = u2h((unsigned)__shfl_xor((int)h2u(v[r]), 32)); v[r] = __hfma2(v[r], sgn, p); } }
}

// XOR-permute 4 words by elo (0..3), compile-time indices only
__device__ __forceinline__ void xorperm4(unsigned int a[4], int elo) {
    bool s0 = (elo & 1) != 0, s1 = (elo & 2) != 0;
    unsigned int t0 = s0 ? a[1] : a[0], t1 = s0 ? a[0] : a[1];
    unsigned int t2 = s0 ? a[3] : a[2], t3 = s0 ? a[2] : a[3];
    a[0] = s1 ? t2 : t0; a[1] = s1 ? t3 : t1;
    a[2] = s1 ? t0 : t2; a[3] = s1 ? t1 : t3;
}

// ================= Pass 1: f32 in -> low-10 WHT (f32 math) -> fp16 ws =================
__global__ __launch_bounds__(256, 4) void p1_kernel(const float* __restrict__ xr,
                                                    const float* __restrict__ xi,
                                                    __half* __restrict__ ws) {
    const int tid = threadIdx.x, lane = tid & 63, w = tid >> 6;
    const int rt = blockIdx.x * 4 + w;              // (batch*1024 + h) in [0,16384)
    const float* re = xr + (size_t)rt * 1024;
    const float* im = xi + (size_t)rt * 1024;
    float vr[16], vi[16];
    #pragma unroll
    for (int q = 0; q < 4; q++) {
        float4 a = *(const float4*)(re + q * 256 + lane * 4);
        float4 b = *(const float4*)(im + q * 256 + lane * 4);
        vr[q*4+0] = a.x * 0.03125f; vr[q*4+1] = a.y * 0.03125f;
        vr[q*4+2] = a.z * 0.03125f; vr[q*4+3] = a.w * 0.03125f;
        vi[q*4+0] = b.x * 0.03125f; vi[q*4+1] = b.y * 0.03125f;
        vi[q*4+2] = b.z * 0.03125f; vi[q*4+3] = b.w * 0.03125f;
    }
    wht16_f32(vr, lane);
    wht16_f32(vi, lane);
    __half* wr = ws + (size_t)rt * 1024;
    __half* wi = ws + (size_t)16 * DIMN + (size_t)rt * 1024;
    #pragma unroll
    for (int q = 0; q < 4; q++) {
        uint2 pr = make_uint2(h2u(__floats2half2_rn(vr[q*4+0], vr[q*4+1])),
                              h2u(__floats2half2_rn(vr[q*4+2], vr[q*4+3])));
        uint2 pi = make_uint2(h2u(__floats2half2_rn(vi[q*4+0], vi[q*4+1])),
                              h2u(__floats2half2_rn(vi[q*4+2], vi[q*4+3])));
        *(uint2*)(wr + q * 256 + lane * 4) = pr;
        *(uint2*)(wi + q * 256 + lane * 4) = pi;
    }
}

// ================= Pass 3: fp16 ws -> low-10 WHT (f32 math) -> f32 out =================
__global__ __launch_bounds__(256, 4) void p3_kernel(const __half* __restrict__ ws,
                                                    float* __restrict__ out) {
    const int tid = threadIdx.x, lane = tid & 63, w = tid >> 6;
    const int rt = blockIdx.x * 4 + w;
    const __half* wr = ws + (size_t)rt * 1024;
    const __half* wi = ws + (size_t)16 * DIMN + (size_t)rt * 1024;
    float vr[16], vi[16];
    #pragma unroll
    for (int q = 0; q < 4; q++) {
        uint2 pr = *(const uint2*)(wr + q * 256 + lane * 4);
        uint2 pi = *(const uint2*)(wi + q * 256 + lane * 4);
        __half2 a0 = u2h(pr.x), a1 = u2h(pr.y), b0 = u2h(pi.x), b1 = u2h(pi.y);
        vr[q*4+0] = __low2float(a0) * 0.03125f; vr[q*4+1] = __high2float(a0) * 0.03125f;
        vr[q*4+2] = __low2float(a1) * 0.03125f; vr[q*4+3] = __high2float(a1) * 0.03125f;
        vi[q*4+0] = __low2float(b0) * 0.03125f; vi[q*4+1] = __high2float(b0) * 0.03125f;
        vi[q*4+2] = __low2float(b1) * 0.03125f; vi[q*4+3] = __high2float(b1) * 0.03125f;
    }
    wht16_f32(vr, lane);
    wht16_f32(vi, lane);
    float* outr = out + (size_t)rt * 1024;
    float* outi = out + (size_t)16 * DIMN + (size_t)rt * 1024;
    #pragma unroll
    for (int q = 0; q < 4; q++) {
        *(float4*)(outr + q * 256 + lane * 4) = make_float4(vr[q*4+0], vr[q*4+1], vr[q*4+2], vr[q*4+3]);
        *(float4*)(outi + q * 256 + lane * 4) = make_float4(vi[q*4+0], vi[q*4+1], vi[q*4+2], vi[q*4+3]);
    }
}

// ================= Pass 2: high-10 WHT + rotate + high-10 WHT, half2(re,im) packed =================
// Tile: [1024 h][8 cols] of half2 = 32 KiB LDS. 512 threads, wave w owns column w.
__global__ __launch_bounds__(512, 4) void p2_kernel(__half* __restrict__ ws,
                                                    const float* __restrict__ tptr) {
    __shared__ unsigned int tile[1024][8];
    const int tid = threadIdx.x, lane = tid & 63, w = tid >> 6;

    // XCD-chunked bijective swizzle (2048 % 8 == 0)
    int wg  = blockIdx.x;
    int swz = (wg & 7) * 256 + (wg >> 3);
    const int b  = swz >> 7;           // batch 0..15
    const int g  = swz & 127;          // column group 0..127
    const int c0 = g * 8;
    const float tval = tptr[0];

    __half* re = ws + (size_t)b * DIMN + c0;
    __half* im = ws + (size_t)16 * DIMN + (size_t)b * DIMN + c0;

    // ---- stage-in: interleave (re,im) -> half2 words, swizzled LDS ----
    #pragma unroll
    for (int it = 0; it < 2; it++) {
        int h = it * 512 + tid;
        uint4 ra = *(const uint4*)(re + (size_t)h * 1024);
        uint4 ia = *(const uint4*)(im + (size_t)h * 1024);
        unsigned int g0[4], g1[4];
        g0[0] = (ra.x & 0xFFFFu) | (ia.x << 16);
        g0[1] = (ra.x >> 16)     | (ia.x & 0xFFFF0000u);
        g0[2] = (ra.y & 0xFFFFu) | (ia.y << 16);
        g0[3] = (ra.y >> 16)     | (ia.y & 0xFFFF0000u);
        g1[0] = (ra.z & 0xFFFFu) | (ia.z << 16);
        g1[1] = (ra.z >> 16)     | (ia.z & 0xFFFF0000u);
        g1[2] = (ra.w & 0xFFFFu) | (ia.w << 16);
        g1[3] = (ra.w >> 16)     | (ia.w & 0xFFFF0000u);
        int e = (h >> 2) & 7;
        xorperm4(g0, e & 3);
        xorperm4(g1, e & 3);
        int ehi = (e >> 2) & 1;
        *(uint4*)&tile[h][ehi ? 4 : 0] = make_uint4(g0[0], g0[1], g0[2], g0[3]);
        *(uint4*)&tile[h][ehi ? 0 : 4] = make_uint4(g1[0], g1[1], g1[2], g1[3]);
    }
    __syncthreads();

    // ---- LDS -> regs: wave w's logical column w (conflict-free: bank = (lane&3)*8 + (w^e)) ----
    const int ecol = w ^ ((lane >> 2) & 7);   // e(h) = (lane>>2)&7 since h = r*64+lane
    const __half2 sc = __float2half2_rn(0.03125f);
    __half2 v[16];
    #pragma unroll
    for (int r = 0; r < 16; r++)
        v[r] = __hmul2(u2h(tile[r * 64 + lane][ecol]), sc);   // pre-scale 2^-5

    // ---- WHT #1 (high 10 bits) ----
    wht16_h2(v, lane);

    // ---- rotation (f32 per element), fold 2^-5 pre-scale for WHT #2 into cs/sn ----
    const int l = c0 + w;
    const int pbase = __popc(lane) + __popc(l);
    float cs[5], sn[5];
    #pragma unroll
    for (int k = 0; k < 5; k++) {
        float ang = tval * (float)(20 - 2 * (pbase + k));
        float s, c;
        sincosf(ang, &s, &c);
        cs[k] = c * 0.03125f;
        sn[k] = s * 0.03125f;
    }
    #pragma unroll
    for (int r = 0; r < 16; r++) {
        const int pr = __popc(r);             // compile-time (r unrolled), 0..4
        float xr = __low2float(v[r]), xi = __high2float(v[r]);
        float yr = cs[pr] * xr + sn[pr] * xi;
        float yi = cs[pr] * xi - sn[pr] * xr;
        v[r] = __floats2half2_rn(yr, yi);
    }

    // ---- WHT #2 (high 10 bits) ----
    wht16_h2(v, lane);

    // ---- regs -> LDS (own column) ----
    #pragma unroll
    for (int r = 0; r < 16; r++)
        tile[r * 64 + lane][ecol] = h2u(v[r]);
    __syncthreads();

    // ---- stage-out: inverse of stage-in ----
    #pragma unroll
    for (int it = 0; it < 2; it++) {
        int h = it * 512 + tid;
        int e = (h >> 2) & 7;
        int ehi = (e >> 2) & 1;
        uint4 u0 = *(const uint4*)&tile[h][ehi ? 4 : 0];
        uint4 u1 = *(const uint4*)&tile[h][ehi ? 0 : 4];
        unsigned int g0[4] = {u0.x, u0.y, u0.z, u0.w};
        unsigned int g1[4] = {u1.x, u1.y, u1.z, u1.w};
        xorperm4(g0, e & 3);
        xorperm4(g1, e & 3);
        uint4 ra, ia;
        ra.x = (g0[0] & 0xFFFFu) | (g0[1] << 16);
        ia.x = (g0[0] >> 16)     | (g0[1] & 0xFFFF0000u);
        ra.y = (g0[2] & 0xFFFFu) | (g0[3] << 16);
        ia.y = (g0[2] >> 16)     | (g0[3] & 0xFFFF0000u);
        ra.z = (g1[0] & 0xFFFFu) | (g1[1] << 16);
        ia.z = (g1[0] >> 16)     | (g1[1] & 0xFFFF0000u);
        ra.w = (g1[2] & 0xFFFFu) | (g1[3] << 16);
        ia.w = (g1[2] >> 16)     | (g1[3] & 0xFFFF0000u);
        *(uint4*)(re + (size_t)h * 1024) = ra;
        *(uint4*)(im + (size_t)h * 1024) = ia;
    }
}

// ================= fp32 fallback (proven R1 path, used only if ws too small) =================
__device__ __forceinline__ void wht10_f4(float4 v[4], int lane) {
    #pragma unroll
    for (int r = 0; r < 4; r++) {
        bf(v[r].x, v[r].y); bf(v[r].z, v[r].w);
        bf(v[r].x, v[r].z); bf(v[r].y, v[r].w);
    }
    #pragma unroll
    for (int m = 1; m <= 32; m <<= 1) {
        float sgn = (lane & m) ? -1.0f : 1.0f;
        #pragma unroll
        for (int r = 0; r < 4; r++) {
            float px = __shfl_xor(v[r].x, m), py = __shfl_xor(v[r].y, m);
            float pz = __shfl_xor(v[r].z, m), pw = __shfl_xor(v[r].w, m);
            v[r].x = fmaf(sgn, v[r].x, px); v[r].y = fmaf(sgn, v[r].y, py);
            v[r].z = fmaf(sgn, v[r].z, pz); v[r].w = fmaf(sgn, v[r].w, pw);
        }
    }
    bf(v[0].x, v[1].x); bf(v[0].y, v[1].y); bf(v[0].z, v[1].z); bf(v[0].w, v[1].w);
    bf(v[2].x, v[3].x); bf(v[2].y, v[3].y); bf(v[2].z, v[3].z); bf(v[2].w, v[3].w);
    bf(v[0].x, v[2].x); bf(v[0].y, v[2].y); bf(v[0].z, v[2].z); bf(v[0].w, v[2].w);
    bf(v[1].x, v[3].x); bf(v[1].y, v[3].y); bf(v[1].z, v[3].z); bf(v[1].w, v[3].w);
}

__global__ __launch_bounds__(256) void pass13_kernel(const float* __restrict__ srcA,
                                                     const float* __restrict__ srcB,
                                                     float* __restrict__ dst) {
    const int tid = threadIdx.x, lane = tid & 63, w = tid >> 6;
    const int rt0 = blockIdx.x * 16 + w * 4;
    const float* src = (rt0 < 16384) ? (srcA + (size_t)rt0 * 1024)
                                     : (srcB + (size_t)(rt0 - 16384) * 1024);
    float* d = dst + (size_t)rt0 * 1024;
    float4 v[4][4];
    #pragma unroll
    for (int rr = 0; rr < 4; rr++)
        #pragma unroll
        for (int r = 0; r < 4; r++)
            v[rr][r] = *(const float4*)(src + rr * 1024 + r * 256 + lane * 4);
    #pragma unroll
    for (int rr = 0; rr < 4; rr++) {
        wht10_f4(v[rr], lane);
        #pragma unroll
        for (int r = 0; r < 4; r++) {
            float4 o;
            o.x = v[rr][r].x * 0.03125f; o.y = v[rr][r].y * 0.03125f;
            o.z = v[rr][r].z * 0.03125f; o.w = v[rr][r].w * 0.03125f;
            *(float4*)(d + rr * 1024 + r * 256 + lane * 4) = o;
        }
    }
}

__global__ __launch_bounds__(256) void pass2_kernel(float* __restrict__ out,
                                                    const float* __restrict__ tptr) {
    __shared__ __align__(16) float tile[2][1024][8];
    const int tid = threadIdx.x, lane = tid & 63, w = tid >> 6;
    int wg = blockIdx.x;
    int swz = (wg & 7) * 256 + (wg >> 3);
    const int b = swz >> 7, g = swz & 127;
    const int c0 = g * 8;
    const float tval = tptr[0];
    float* baseR = out + (size_t)b * DIMN;
    float* baseI = out + (size_t)16 * DIMN + (size_t)b * DIMN;
    float4 tmp[2][8];
    #pragma unroll
    for (int comp = 0; comp < 2; comp++) {
        const float* src = comp ? baseI : baseR;
        #pragma unroll
        for (int it = 0; it < 8; it++) {
            int f4id = it * 256 + tid;
            int h = f4id >> 1, q = f4id & 1;
            tmp[comp][it] = *(const float4*)(src + (size_t)h * 1024 + c0 + q * 4);
        }
    }
    #pragma unroll
    for (int comp = 0; comp < 2; comp++) {
        #pragma unroll
        for (int it = 0; it < 8; it++) {
            int f4id = it * 256 + tid;
            int h = f4id >> 1, q = f4id & 1;
            int e = (h >> 2) & 7, elo = e & 3;
            float4 val = tmp[comp][it];
            bool s0 = (elo & 1) != 0;
            float x1 = s0 ? val.y : val.x, y1 = s0 ? val.x : val.y;
            float z1 = s0 ? val.w : val.z, w1 = s0 ? val.z : val.w;
            bool s1 = (elo & 2) != 0;
            float x2 = s1 ? z1 : x1, y2 = s1 ? w1 : y1;
            float z2 = s1 ? x1 : z1, w2 = s1 ? y1 : w1;
            int qp = q ^ (e >> 2);
            *(float4*)&tile[comp][h][qp * 4] = make_float4(x2, y2, z2, w2);
        }
    }
    __syncthreads();
    float vr[2][16], vi[2][16];
    #pragma unroll
    for (int r = 0; r < 16; r++) {
        int h = r * 64 + lane;
        int e = (lane >> 2) & 7;
        #pragma unroll
        for (int cc = 0; cc < 2; cc++) {
            int cp = (2 * w + cc) ^ e;
            vr[cc][r] = tile[0][h][cp];
            vi[cc][r] = tile[1][h][cp];
        }
    }
    const int pcl = __popc(lane);
    #pragma unroll
    for (int cc = 0; cc < 2; cc++) {
        wht16_f32(vr[cc], lane);
        wht16_f32(vi[cc], lane);
        const int cg = c0 + 2 * w + cc;
        const int pbase = pcl + __popc(cg);
        float csk[5], snk[5];
        #pragma unroll
        for (int k = 0; k < 5; k++) {
            float ang = tval * (float)(20 - 2 * (pbase + k));
            sincosf(ang, &snk[k], &csk[k]);
        }
        #pragma unroll
        for (int r = 0; r < 16; r++) {
            const int pr = __popc(r);
            float cv = csk[pr], sv = snk[pr];
            float xr = vr[cc][r] * 0.03125f, xi = vi[cc][r] * 0.03125f;
            vr[cc][r] = fmaf(cv, xr, sv * xi);
            vi[cc][r] = fmaf(cv, xi, -sv * xr);
        }
        wht16_f32(vr[cc], lane);
        wht16_f32(vi[cc], lane);
    }
    #pragma unroll
    for (int r = 0; r < 16; r++) {
        int h = r * 64 + lane;
        int e = (lane >> 2) & 7;
        #pragma unroll
        for (int cc = 0; cc < 2; cc++) {
            int cp = (2 * w + cc) ^ e;
            tile[0][h][cp] = vr[cc][r] * 0.03125f;
            tile[1][h][cp] = vi[cc][r] * 0.03125f;
        }
    }
    __syncthreads();
    #pragma unroll
    for (int comp = 0; comp < 2; comp++) {
        float* dstg = comp ? baseI : baseR;
        #pragma unroll
        for (int it = 0; it < 8; it++) {
            int f4id = it * 256 + tid;
            int h = f4id >> 1, q = f4id & 1;
            int e = (h >> 2) & 7, elo = e & 3;
            int qp = q ^ (e >> 2);
            float4 sv = *(const float4*)&tile[comp][h][qp * 4];
            bool s0 = (elo & 1) != 0;
            float x1 = s0 ? sv.y : sv.x, y1 = s0 ? sv.x : sv.y;
            float z1 = s0 ? sv.w : sv.z, w1 = s0 ? sv.z : sv.w;
            bool s1 = (elo & 2) != 0;
            float x2 = s1 ? z1 : x1, y2 = s1 ? w1 : y1;
            float z2 = s1 ? x1 : z1, w2 = s1 ? y1 : w1;
            *(float4*)(dstg + (size_t)h * 1024 + c0 + q * 4) = make_float4(x2, y2, z2, w2);
        }
    }
}

extern "C" void kernel_launch(void* const* d_in, const int* in_sizes, int n_in,
                              void* d_out, int out_size, void* d_ws, size_t ws_size,
                              hipStream_t stream) {
    const float* xr = (const float*)d_in[0];
    const float* xi = (const float*)d_in[1];
    const float* t  = (const float*)d_in[2];
    float* out = (float*)d_out;

    const size_t need = (size_t)2 * 16 * DIMN * sizeof(__half);  // 64 MiB
    if (ws_size >= need) {
        __half* ws = (__half*)d_ws;
        p1_kernel<<<4096, 256, 0, stream>>>(xr, xi, ws);
        p2_kernel<<<2048, 512, 0, stream>>>(ws, t);
        p3_kernel<<<4096, 256, 0, stream>>>(ws, out);
    } else {
        pass13_kernel<<<2048, 256, 0, stream>>>(xr, xi, out);
        pass2_kernel<<<2048, 256, 0, stream>>>(out, t);
        pass13_kernel<<<2048, 256, 0, stream>>>(out, out + (size_t)16 * DIMN, out);
    }
}

// Round 5
// 119.117 us; speedup vs baseline: 1.5049x; 1.0181x over previous
//
#include <hip/hip_runtime.h>
#include <hip/hip_fp16.h>
#include <math.h>

#define DIMN (1 << 20)   // 2^20 per batch row
// d_out: [2][16][DIMN] f32.  d_ws (fp16 path): [2][16][DIMN] __half.

typedef unsigned int uint2v __attribute__((ext_vector_type(2)));

// ---------------- bit-cast helpers ----------------
__device__ __forceinline__ unsigned int h2u(__half2 v){ union{__half2 h; unsigned int u;} x; x.h=v; return x.u; }
__device__ __forceinline__ __half2 u2h(unsigned int v){ union{unsigned int u; __half2 h;} x; x.u=v; return x.h; }

__device__ __forceinline__ void bf(float& a, float& b) { float s = a + b; b = a - b; a = s; }

// ---------------- DPP lane-exchange (VALU pipe, not DS) ----------------
// xor1 = quad_perm[1,0,3,2] = 0xB1 ; xor2 = quad_perm[2,3,0,1] = 0x4E ;
// xor8 = row_ror:8 = 0x128
template<int CTRL>
__device__ __forceinline__ float dppf(float x) {
    return __int_as_float(__builtin_amdgcn_mov_dpp(__float_as_int(x), CTRL, 0xF, 0xF, true));
}
template<int CTRL>
__device__ __forceinline__ unsigned int dppu(unsigned int x) {
    return (unsigned int)__builtin_amdgcn_mov_dpp((int)x, CTRL, 0xF, 0xF, true);
}

// ---------------- permlane swap butterflies (VALU pipe) ----------------
// permlaneN_swap(x,x) -> a = own-half duplicated, b = other-half duplicated;
// butterfly = a + sgn*b, sgn = (lane&m)?-1:+1. Bit-identical to shfl form.
__device__ __forceinline__ float bfly16_f(float x, float sgn) {
#if __has_builtin(__builtin_amdgcn_permlane16_swap)
    uint2v r = __builtin_amdgcn_permlane16_swap(__float_as_uint(x), __float_as_uint(x), false, false);
    return fmaf(sgn, __uint_as_float(r.y), __uint_as_float(r.x));
#else
    float p = __shfl_xor(x, 16);
    return fmaf(sgn, x, p);
#endif
}
__device__ __forceinline__ float bfly32_f(float x, float sgn) {
#if __has_builtin(__builtin_amdgcn_permlane32_swap)
    uint2v r = __builtin_amdgcn_permlane32_swap(__float_as_uint(x), __float_as_uint(x), false, false);
    return fmaf(sgn, __uint_as_float(r.y), __uint_as_float(r.x));
#else
    float p = __shfl_xor(x, 32);
    return fmaf(sgn, x, p);
#endif
}
__device__ __forceinline__ __half2 bfly16_h2(__half2 x, __half2 sgn) {
#if __has_builtin(__builtin_amdgcn_permlane16_swap)
    uint2v r = __builtin_amdgcn_permlane16_swap(h2u(x), h2u(x), false, false);
    return __hfma2(u2h(r.y), sgn, u2h(r.x));
#else
    __half2 p = u2h((unsigned)__shfl_xor((int)h2u(x), 16));
    return __hfma2(x, sgn, p);
#endif
}
__device__ __forceinline__ __half2 bfly32_h2(__half2 x, __half2 sgn) {
#if __has_builtin(__builtin_amdgcn_permlane32_swap)
    uint2v r = __builtin_amdgcn_permlane32_swap(h2u(x), h2u(x), false, false);
    return __hfma2(u2h(r.y), sgn, u2h(r.x));
#else
    __half2 p = u2h((unsigned)__shfl_xor((int)h2u(x), 32));
    return __hfma2(x, sgn, p);
#endif
}

// ---------------- f32 WHT over 10 bits ----------------
// reg pairing s = 1,2,4,8 over whatever element-bits the regs carry;
// lane masks 1..32 over 6 lane bits. Only mask 4 remains on the DS pipe.
__device__ __forceinline__ void wht16_f32(float v[16], int lane) {
    #pragma unroll
    for (int s = 1; s < 16; s <<= 1)
        #pragma unroll
        for (int r = 0; r < 16; r++)
            if (!(r & s)) bf(v[r], v[r ^ s]);
    {   float sgn = (lane & 1) ? -1.0f : 1.0f;
        #pragma unroll
        for (int r = 0; r < 16; r++) { float p = dppf<0xB1>(v[r]); v[r] = fmaf(sgn, v[r], p); } }
    {   float sgn = (lane & 2) ? -1.0f : 1.0f;
        #pragma unroll
        for (int r = 0; r < 16; r++) { float p = dppf<0x4E>(v[r]); v[r] = fmaf(sgn, v[r], p); } }
    {   float sgn = (lane & 4) ? -1.0f : 1.0f;
        #pragma unroll
        for (int r = 0; r < 16; r++) { float p = __shfl_xor(v[r], 4); v[r] = fmaf(sgn, v[r], p); } }
    {   float sgn = (lane & 8) ? -1.0f : 1.0f;
        #pragma unroll
        for (int r = 0; r < 16; r++) { float p = dppf<0x128>(v[r]); v[r] = fmaf(sgn, v[r], p); } }
    {   float sgn = (lane & 16) ? -1.0f : 1.0f;
        #pragma unroll
        for (int r = 0; r < 16; r++) v[r] = bfly16_f(v[r], sgn); }
    {   float sgn = (lane & 32) ? -1.0f : 1.0f;
        #pragma unroll
        for (int r = 0; r < 16; r++) v[r] = bfly32_f(v[r], sgn); }
}

// ---------------- half2 (re,im)-packed WHT over 10 bits ----------------
__device__ __forceinline__ void wht16_h2(__half2 v[16], int lane) {
    #pragma unroll
    for (int s = 1; s < 16; s <<= 1)
        #pragma unroll
        for (int r = 0; r < 16; r++)
            if (!(r & s)) {
                __half2 t = __hadd2(v[r], v[r ^ s]);
                v[r ^ s]  = __hsub2(v[r], v[r ^ s]);
                v[r] = t;
            }
    {   __half2 sgn = __float2half2_rn((lane & 1) ? -1.0f : 1.0f);
        #pragma unroll
        for (int r = 0; r < 16; r++) { __half2 p = u2h(dppu<0xB1>(h2u(v[r]))); v[r] = __hfma2(v[r], sgn, p); } }
    {   __half2 sgn = __float2half2_rn((lane & 2) ? -1.0f : 1.0f);
        #pragma unroll
        for (int r = 0; r < 16; r++) { __half2 p = u2h(dppu<0x4E>(h2u(v[r]))); v[r] = __hfma2(v[r], sgn, p); } }
    {   __half2 sgn = __float2half2_rn((lane & 4) ? -1.0f : 1.0f);
        #pragma unroll
        for (int r = 0; r < 16; r++) { __half2 p = u2h((unsigned)__shfl_xor((int)h2u(v[r]), 4)); v[r] = __hfma2(v[r], sgn, p); } }
    {   __half2 sgn = __float2half2_rn((lane & 8) ? -1.0f : 1.0f);
        #pragma unroll
        for (int r = 0; r < 16; r++) { __half2 p = u2h(dppu<0x128>(h2u(v[r]))); v[r] = __hfma2(v[r], sgn, p); } }
    {   __half2 sgn = __float2half2_rn((lane & 16) ? -1.0f : 1.0f);
        #pragma unroll
        for (int r = 0; r < 16; r++) v[r] = bfly16_h2(v[r], sgn); }
    {   __half2 sgn = __float2half2_rn((lane & 32) ? -1.0f : 1.0f);
        #pragma unroll
        for (int r = 0; r < 16; r++) v[r] = bfly32_h2(v[r], sgn); }
}

// XOR-permute 4 words by elo (0..3), compile-time indices only
__device__ __forceinline__ void xorperm4(unsigned int a[4], int elo) {
    bool s0 = (elo & 1) != 0, s1 = (elo & 2) != 0;
    unsigned int t0 = s0 ? a[1] : a[0], t1 = s0 ? a[0] : a[1];
    unsigned int t2 = s0 ? a[3] : a[2], t3 = s0 ? a[2] : a[3];
    a[0] = s1 ? t2 : t0; a[1] = s1 ? t3 : t1;
    a[2] = s1 ? t0 : t2; a[3] = s1 ? t1 : t3;
}

// ================= Pass 1: f32 in -> low-10 WHT (f32 math) -> fp16 ws =================
// layout: element l = q*512 + lane*8 + s  (reg r = q*8+s; elem bits {0,1,2,9} in regs)
__global__ __launch_bounds__(256, 4) void p1_kernel(const float* __restrict__ xr,
                                                    const float* __restrict__ xi,
                                                    __half* __restrict__ ws) {
    const int tid = threadIdx.x, lane = tid & 63, w = tid >> 6;
    const int rt = blockIdx.x * 4 + w;              // (batch*1024 + h) in [0,16384)
    const float* re = xr + (size_t)rt * 1024;
    const float* im = xi + (size_t)rt * 1024;
    float vr[16], vi[16];
    #pragma unroll
    for (int q = 0; q < 2; q++) {
        const int base = q * 512 + lane * 8;
        float4 a0 = *(const float4*)(re + base);
        float4 a1 = *(const float4*)(re + base + 4);
        float4 b0 = *(const float4*)(im + base);
        float4 b1 = *(const float4*)(im + base + 4);
        vr[q*8+0]=a0.x*0.03125f; vr[q*8+1]=a0.y*0.03125f; vr[q*8+2]=a0.z*0.03125f; vr[q*8+3]=a0.w*0.03125f;
        vr[q*8+4]=a1.x*0.03125f; vr[q*8+5]=a1.y*0.03125f; vr[q*8+6]=a1.z*0.03125f; vr[q*8+7]=a1.w*0.03125f;
        vi[q*8+0]=b0.x*0.03125f; vi[q*8+1]=b0.y*0.03125f; vi[q*8+2]=b0.z*0.03125f; vi[q*8+3]=b0.w*0.03125f;
        vi[q*8+4]=b1.x*0.03125f; vi[q*8+5]=b1.y*0.03125f; vi[q*8+6]=b1.z*0.03125f; vi[q*8+7]=b1.w*0.03125f;
    }
    wht16_f32(vr, lane);
    wht16_f32(vi, lane);
    __half* wr = ws + (size_t)rt * 1024;
    __half* wi = ws + (size_t)16 * DIMN + (size_t)rt * 1024;
    #pragma unroll
    for (int q = 0; q < 2; q++) {
        const int base = q * 512 + lane * 8;
        uint4 pr, pi;
        pr.x = h2u(__floats2half2_rn(vr[q*8+0], vr[q*8+1]));
        pr.y = h2u(__floats2half2_rn(vr[q*8+2], vr[q*8+3]));
        pr.z = h2u(__floats2half2_rn(vr[q*8+4], vr[q*8+5]));
        pr.w = h2u(__floats2half2_rn(vr[q*8+6], vr[q*8+7]));
        pi.x = h2u(__floats2half2_rn(vi[q*8+0], vi[q*8+1]));
        pi.y = h2u(__floats2half2_rn(vi[q*8+2], vi[q*8+3]));
        pi.z = h2u(__floats2half2_rn(vi[q*8+4], vi[q*8+5]));
        pi.w = h2u(__floats2half2_rn(vi[q*8+6], vi[q*8+7]));
        *(uint4*)(wr + base) = pr;
        *(uint4*)(wi + base) = pi;
    }
}

// ================= Pass 3: fp16 ws -> low-10 WHT (f32 math) -> f32 out =================
__global__ __launch_bounds__(256, 4) void p3_kernel(const __half* __restrict__ ws,
                                                    float* __restrict__ out) {
    const int tid = threadIdx.x, lane = tid & 63, w = tid >> 6;
    const int rt = blockIdx.x * 4 + w;
    const __half* wr = ws + (size_t)rt * 1024;
    const __half* wi = ws + (size_t)16 * DIMN + (size_t)rt * 1024;
    float vr[16], vi[16];
    #pragma unroll
    for (int q = 0; q < 2; q++) {
        const int base = q * 512 + lane * 8;
        uint4 pr = *(const uint4*)(wr + base);
        uint4 pi = *(const uint4*)(wi + base);
        __half2 a0=u2h(pr.x), a1=u2h(pr.y), a2=u2h(pr.z), a3=u2h(pr.w);
        __half2 b0=u2h(pi.x), b1=u2h(pi.y), b2=u2h(pi.z), b3=u2h(pi.w);
        vr[q*8+0]=__low2float(a0)*0.03125f; vr[q*8+1]=__high2float(a0)*0.03125f;
        vr[q*8+2]=__low2float(a1)*0.03125f; vr[q*8+3]=__high2float(a1)*0.03125f;
        vr[q*8+4]=__low2float(a2)*0.03125f; vr[q*8+5]=__high2float(a2)*0.03125f;
        vr[q*8+6]=__low2float(a3)*0.03125f; vr[q*8+7]=__high2float(a3)*0.03125f;
        vi[q*8+0]=__low2float(b0)*0.03125f; vi[q*8+1]=__high2float(b0)*0.03125f;
        vi[q*8+2]=__low2float(b1)*0.03125f; vi[q*8+3]=__high2float(b1)*0.03125f;
        vi[q*8+4]=__low2float(b2)*0.03125f; vi[q*8+5]=__high2float(b2)*0.03125f;
        vi[q*8+6]=__low2float(b3)*0.03125f; vi[q*8+7]=__high2float(b3)*0.03125f;
    }
    wht16_f32(vr, lane);
    wht16_f32(vi, lane);
    float* outr = out + (size_t)rt * 1024;
    float* outi = out + (size_t)16 * DIMN + (size_t)rt * 1024;
    #pragma unroll
    for (int q = 0; q < 2; q++) {
        const int base = q * 512 + lane * 8;
        *(float4*)(outr + base)     = make_float4(vr[q*8+0], vr[q*8+1], vr[q*8+2], vr[q*8+3]);
        *(float4*)(outr + base + 4) = make_float4(vr[q*8+4], vr[q*8+5], vr[q*8+6], vr[q*8+7]);
        *(float4*)(outi + base)     = make_float4(vi[q*8+0], vi[q*8+1], vi[q*8+2], vi[q*8+3]);
        *(float4*)(outi + base + 4) = make_float4(vi[q*8+4], vi[q*8+5], vi[q*8+6], vi[q*8+7]);
    }
}

// ================= Pass 2: high-10 WHT + rotate + high-10 WHT, half2(re,im) packed =================
// Tile: [1024 h][8 cols] of half2 = 32 KiB LDS. 512 threads, wave w owns column w.
__global__ __launch_bounds__(512, 4) void p2_kernel(__half* __restrict__ ws,
                                                    const float* __restrict__ tptr) {
    __shared__ unsigned int tile[1024][8];
    const int tid = threadIdx.x, lane = tid & 63, w = tid >> 6;

    // XCD-chunked bijective swizzle (2048 % 8 == 0)
    int wg  = blockIdx.x;
    int swz = (wg & 7) * 256 + (wg >> 3);
    const int b  = swz >> 7;           // batch 0..15
    const int g  = swz & 127;          // column group 0..127
    const int c0 = g * 8;
    const float tval = tptr[0];

    __half* re = ws + (size_t)b * DIMN + c0;
    __half* im = ws + (size_t)16 * DIMN + (size_t)b * DIMN + c0;

    // ---- stage-in: interleave (re,im) -> half2 words, swizzled LDS ----
    #pragma unroll
    for (int it = 0; it < 2; it++) {
        int h = it * 512 + tid;
        uint4 ra = *(const uint4*)(re + (size_t)h * 1024);
        uint4 ia = *(const uint4*)(im + (size_t)h * 1024);
        unsigned int g0[4], g1[4];
        g0[0] = (ra.x & 0xFFFFu) | (ia.x << 16);
        g0[1] = (ra.x >> 16)     | (ia.x & 0xFFFF0000u);
        g0[2] = (ra.y & 0xFFFFu) | (ia.y << 16);
        g0[3] = (ra.y >> 16)     | (ia.y & 0xFFFF0000u);
        g1[0] = (ra.z & 0xFFFFu) | (ia.z << 16);
        g1[1] = (ra.z >> 16)     | (ia.z & 0xFFFF0000u);
        g1[2] = (ra.w & 0xFFFFu) | (ia.w << 16);
        g1[3] = (ra.w >> 16)     | (ia.w & 0xFFFF0000u);
        int e = (h >> 2) & 7;
        xorperm4(g0, e & 3);
        xorperm4(g1, e & 3);
        int ehi = (e >> 2) & 1;
        *(uint4*)&tile[h][ehi ? 4 : 0] = make_uint4(g0[0], g0[1], g0[2], g0[3]);
        *(uint4*)&tile[h][ehi ? 0 : 4] = make_uint4(g1[0], g1[1], g1[2], g1[3]);
    }
    __syncthreads();

    // ---- LDS -> regs: wave w's logical column w (conflict-free) ----
    const int ecol = w ^ ((lane >> 2) & 7);
    const __half2 sc = __float2half2_rn(0.03125f);
    __half2 v[16];
    #pragma unroll
    for (int r = 0; r < 16; r++)
        v[r] = __hmul2(u2h(tile[r * 64 + lane][ecol]), sc);   // pre-scale 2^-5

    // ---- WHT #1 (high 10 bits) ----
    wht16_h2(v, lane);

    // ---- rotation (f32), fold 2^-5 pre-scale for WHT #2 into cs/sn ----
    const int l = c0 + w;
    const int pbase = __popc(lane) + __popc(l);
    float cs[5], sn[5];
    #pragma unroll
    for (int k = 0; k < 5; k++) {
        float ang = tval * (float)(20 - 2 * (pbase + k));
        float s, c;
        sincosf(ang, &s, &c);
        cs[k] = c * 0.03125f;
        sn[k] = s * 0.03125f;
    }
    #pragma unroll
    for (int r = 0; r < 16; r++) {
        const int pr = __popc(r);
        float xr = __low2float(v[r]), xi = __high2float(v[r]);
        float yr = cs[pr] * xr + sn[pr] * xi;
        float yi = cs[pr] * xi - sn[pr] * xr;
        v[r] = __floats2half2_rn(yr, yi);
    }

    // ---- WHT #2 (high 10 bits) ----
    wht16_h2(v, lane);

    // ---- regs -> LDS (own column) ----
    #pragma unroll
    for (int r = 0; r < 16; r++)
        tile[r * 64 + lane][ecol] = h2u(v[r]);
    __syncthreads();

    // ---- stage-out: inverse of stage-in ----
    #pragma unroll
    for (int it = 0; it < 2; it++) {
        int h = it * 512 + tid;
        int e = (h >> 2) & 7;
        int ehi = (e >> 2) & 1;
        uint4 u0 = *(const uint4*)&tile[h][ehi ? 4 : 0];
        uint4 u1 = *(const uint4*)&tile[h][ehi ? 0 : 4];
        unsigned int g0[4] = {u0.x, u0.y, u0.z, u0.w};
        unsigned int g1[4] = {u1.x, u1.y, u1.z, u1.w};
        xorperm4(g0, e & 3);
        xorperm4(g1, e & 3);
        uint4 ra, ia;
        ra.x = (g0[0] & 0xFFFFu) | (g0[1] << 16);
        ia.x = (g0[0] >> 16)     | (g0[1] & 0xFFFF0000u);
        ra.y = (g0[2] & 0xFFFFu) | (g0[3] << 16);
        ia.y = (g0[2] >> 16)     | (g0[3] & 0xFFFF0000u);
        ra.z = (g1[0] & 0xFFFFu) | (g1[1] << 16);
        ia.z = (g1[0] >> 16)     | (g1[1] & 0xFFFF0000u);
        ra.w = (g1[2] & 0xFFFFu) | (g1[3] << 16);
        ia.w = (g1[2] >> 16)     | (g1[3] & 0xFFFF0000u);
        *(uint4*)(re + (size_t)h * 1024) = ra;
        *(uint4*)(im + (size_t)h * 1024) = ia;
    }
}

// ================= fp32 fallback (proven path, used only if ws too small) =================
__device__ __forceinline__ void wht10_f4(float4 v[4], int lane) {
    #pragma unroll
    for (int r = 0; r < 4; r++) {
        bf(v[r].x, v[r].y); bf(v[r].z, v[r].w);
        bf(v[r].x, v[r].z); bf(v[r].y, v[r].w);
    }
    #pragma unroll
    for (int m = 1; m <= 32; m <<= 1) {
        float sgn = (lane & m) ? -1.0f : 1.0f;
        #pragma unroll
        for (int r = 0; r < 4; r++) {
            float px = __shfl_xor(v[r].x, m), py = __shfl_xor(v[r].y, m);
            float pz = __shfl_xor(v[r].z, m), pw = __shfl_xor(v[r].w, m);
            v[r].x = fmaf(sgn, v[r].x, px); v[r].y = fmaf(sgn, v[r].y, py);
            v[r].z = fmaf(sgn, v[r].z, pz); v[r].w = fmaf(sgn, v[r].w, pw);
        }
    }
    bf(v[0].x, v[1].x); bf(v[0].y, v[1].y); bf(v[0].z, v[1].z); bf(v[0].w, v[1].w);
    bf(v[2].x, v[3].x); bf(v[2].y, v[3].y); bf(v[2].z, v[3].z); bf(v[2].w, v[3].w);
    bf(v[0].x, v[2].x); bf(v[0].y, v[2].y); bf(v[0].z, v[2].z); bf(v[0].w, v[2].w);
    bf(v[1].x, v[3].x); bf(v[1].y, v[3].y); bf(v[1].z, v[3].z); bf(v[1].w, v[3].w);
}

__global__ __launch_bounds__(256) void pass13_kernel(const float* __restrict__ srcA,
                                                     const float* __restrict__ srcB,
                                                     float* __restrict__ dst) {
    const int tid = threadIdx.x, lane = tid & 63, w = tid >> 6;
    const int rt0 = blockIdx.x * 16 + w * 4;
    const float* src = (rt0 < 16384) ? (srcA + (size_t)rt0 * 1024)
                                     : (srcB + (size_t)(rt0 - 16384) * 1024);
    float* d = dst + (size_t)rt0 * 1024;
    float4 v[4][4];
    #pragma unroll
    for (int rr = 0; rr < 4; rr++)
        #pragma unroll
        for (int r = 0; r < 4; r++)
            v[rr][r] = *(const float4*)(src + rr * 1024 + r * 256 + lane * 4);
    #pragma unroll
    for (int rr = 0; rr < 4; rr++) {
        wht10_f4(v[rr], lane);
        #pragma unroll
        for (int r = 0; r < 4; r++) {
            float4 o;
            o.x = v[rr][r].x * 0.03125f; o.y = v[rr][r].y * 0.03125f;
            o.z = v[rr][r].z * 0.03125f; o.w = v[rr][r].w * 0.03125f;
            *(float4*)(d + rr * 1024 + r * 256 + lane * 4) = o;
        }
    }
}

__global__ __launch_bounds__(256) void pass2_kernel(float* __restrict__ out,
                                                    const float* __restrict__ tptr) {
    __shared__ __align__(16) float tile[2][1024][8];
    const int tid = threadIdx.x, lane = tid & 63, w = tid >> 6;
    int wg = blockIdx.x;
    int swz = (wg & 7) * 256 + (wg >> 3);
    const int b = swz >> 7, g = swz & 127;
    const int c0 = g * 8;
    const float tval = tptr[0];
    float* baseR = out + (size_t)b * DIMN;
    float* baseI = out + (size_t)16 * DIMN + (size_t)b * DIMN;
    float4 tmp[2][8];
    #pragma unroll
    for (int comp = 0; comp < 2; comp++) {
        const float* src = comp ? baseI : baseR;
        #pragma unroll
        for (int it = 0; it < 8; it++) {
            int f4id = it * 256 + tid;
            int h = f4id >> 1, q = f4id & 1;
            tmp[comp][it] = *(const float4*)(src + (size_t)h * 1024 + c0 + q * 4);
        }
    }
    #pragma unroll
    for (int comp = 0; comp < 2; comp++) {
        #pragma unroll
        for (int it = 0; it < 8; it++) {
            int f4id = it * 256 + tid;
            int h = f4id >> 1, q = f4id & 1;
            int e = (h >> 2) & 7, elo = e & 3;
            float4 val = tmp[comp][it];
            bool s0 = (elo & 1) != 0;
            float x1 = s0 ? val.y : val.x, y1 = s0 ? val.x : val.y;
            float z1 = s0 ? val.w : val.z, w1 = s0 ? val.z : val.w;
            bool s1 = (elo & 2) != 0;
            float x2 = s1 ? z1 : x1, y2 = s1 ? w1 : y1;
            float z2 = s1 ? x1 : z1, w2 = s1 ? y1 : w1;
            int qp = q ^ (e >> 2);
            *(float4*)&tile[comp][h][qp * 4] = make_float4(x2, y2, z2, w2);
        }
    }
    __syncthreads();
    float vr[2][16], vi[2][16];
    #pragma unroll
    for (int r = 0; r < 16; r++) {
        int h = r * 64 + lane;
        int e = (lane >> 2) & 7;
        #pragma unroll
        for (int cc = 0; cc < 2; cc++) {
            int cp = (2 * w + cc) ^ e;
            vr[cc][r] = tile[0][h][cp];
            vi[cc][r] = tile[1][h][cp];
        }
    }
    const int pcl = __popc(lane);
    #pragma unroll
    for (int cc = 0; cc < 2; cc++) {
        wht16_f32(vr[cc], lane);
        wht16_f32(vi[cc], lane);
        const int cg = c0 + 2 * w + cc;
        const int pbase = pcl + __popc(cg);
        float csk[5], snk[5];
        #pragma unroll
        for (int k = 0; k < 5; k++) {
            float ang = tval * (float)(20 - 2 * (pbase + k));
            sincosf(ang, &snk[k], &csk[k]);
        }
        #pragma unroll
        for (int r = 0; r < 16; r++) {
            const int pr = __popc(r);
            float cv = csk[pr], sv = snk[pr];
            float xr = vr[cc][r] * 0.03125f, xi = vi[cc][r] * 0.03125f;
            vr[cc][r] = fmaf(cv, xr, sv * xi);
            vi[cc][r] = fmaf(cv, xi, -sv * xr);
        }
        wht16_f32(vr[cc], lane);
        wht16_f32(vi[cc], lane);
    }
    #pragma unroll
    for (int r = 0; r < 16; r++) {
        int h = r * 64 + lane;
        int e = (lane >> 2) & 7;
        #pragma unroll
        for (int cc = 0; cc < 2; cc++) {
            int cp = (2 * w + cc) ^ e;
            tile[0][h][cp] = vr[cc][r] * 0.03125f;
            tile[1][h][cp] = vi[cc][r] * 0.03125f;
        }
    }
    __syncthreads();
    #pragma unroll
    for (int comp = 0; comp < 2; comp++) {
        float* dstg = comp ? baseI : baseR;
        #pragma unroll
        for (int it = 0; it < 8; it++) {
            int f4id = it * 256 + tid;
            int h = f4id >> 1, q = f4id & 1;
            int e = (h >> 2) & 7, elo = e & 3;
            int qp = q ^ (e >> 2);
            float4 sv = *(const float4*)&tile[comp][h][qp * 4];
            bool s0 = (elo & 1) != 0;
            float x1 = s0 ? sv.y : sv.x, y1 = s0 ? sv.x : sv.y;
            float z1 = s0 ? sv.w : sv.z, w1 = s0 ? sv.z : sv.w;
            bool s1 = (elo & 2) != 0;
            float x2 = s1 ? z1 : x1, y2 = s1 ? w1 : y1;
            float z2 = s1 ? x1 : z1, w2 = s1 ? y1 : w1;
            *(float4*)(dstg + (size_t)h * 1024 + c0 + q * 4) = make_float4(x2, y2, z2, w2);
        }
    }
}

extern "C" void kernel_launch(void* const* d_in, const int* in_sizes, int n_in,
                              void* d_out, int out_size, void* d_ws, size_t ws_size,
                              hipStream_t stream) {
    const float* xr = (const float*)d_in[0];
    const float* xi = (const float*)d_in[1];
    const float* t  = (const float*)d_in[2];
    float* out = (float*)d_out;

    const size_t need = (size_t)2 * 16 * DIMN * sizeof(__half);  // 64 MiB
    if (ws_size >= need) {
        __half* ws = (__half*)d_ws;
        p1_kernel<<<4096, 256, 0, stream>>>(xr, xi, ws);
        p2_kernel<<<2048, 512, 0, stream>>>(ws, t);
        p3_kernel<<<4096, 256, 0, stream>>>(ws, out);
    } else {
        pass13_kernel<<<2048, 256, 0, stream>>>(xr, xi, out);
        pass2_kernel<<<2048, 256, 0, stream>>>(out, t);
        pass13_kernel<<<2048, 256, 0, stream>>>(out, out + (size_t)16 * DIMN, out);
    }
}

// Round 6
// 118.580 us; speedup vs baseline: 1.5117x; 1.0045x over previous
//
#include <hip/hip_runtime.h>
#include <hip/hip_fp16.h>
#include <math.h>

#define DIMN (1 << 20)   // 2^20 per batch row
// d_out: [2][16][DIMN] f32.  d_ws (fp16 path): [2][16][DIMN] __half.

typedef unsigned int uint2v __attribute__((ext_vector_type(2)));

// ---------------- bit-cast helpers ----------------
__device__ __forceinline__ unsigned int h2u(__half2 v){ union{__half2 h; unsigned int u;} x; x.h=v; return x.u; }
__device__ __forceinline__ __half2 u2h(unsigned int v){ union{unsigned int u; __half2 h;} x; x.u=v; return x.h; }

__device__ __forceinline__ void bf(float& a, float& b) { float s = a + b; b = a - b; a = s; }

// ---------------- DPP lane-exchange (VALU pipe, not DS) ----------------
// xor1 = quad_perm[1,0,3,2] = 0xB1 ; xor2 = quad_perm[2,3,0,1] = 0x4E ;
// xor8 = row_ror:8 = 0x128 ; xor4 = quad_perm[3,2,1,0](row_half_mirror(x))
//   (0x1B after 0x141: x[(i^3)^7] = x[i^4], both direction-unambiguous)
template<int CTRL>
__device__ __forceinline__ float dppf(float x) {
    return __int_as_float(__builtin_amdgcn_mov_dpp(__float_as_int(x), CTRL, 0xF, 0xF, true));
}
template<int CTRL>
__device__ __forceinline__ unsigned int dppu(unsigned int x) {
    return (unsigned int)__builtin_amdgcn_mov_dpp((int)x, CTRL, 0xF, 0xF, true);
}
__device__ __forceinline__ float xor4_f(float x) { return dppf<0x1B>(dppf<0x141>(x)); }
__device__ __forceinline__ unsigned int xor4_u(unsigned int x) { return dppu<0x1B>(dppu<0x141>(x)); }

// ---------------- permlane swap butterflies (VALU pipe) ----------------
__device__ __forceinline__ float bfly16_f(float x, float sgn) {
#if __has_builtin(__builtin_amdgcn_permlane16_swap)
    uint2v r = __builtin_amdgcn_permlane16_swap(__float_as_uint(x), __float_as_uint(x), false, false);
    return fmaf(sgn, __uint_as_float(r.y), __uint_as_float(r.x));
#else
    float p = __shfl_xor(x, 16);
    return fmaf(sgn, x, p);
#endif
}
__device__ __forceinline__ float bfly32_f(float x, float sgn) {
#if __has_builtin(__builtin_amdgcn_permlane32_swap)
    uint2v r = __builtin_amdgcn_permlane32_swap(__float_as_uint(x), __float_as_uint(x), false, false);
    return fmaf(sgn, __uint_as_float(r.y), __uint_as_float(r.x));
#else
    float p = __shfl_xor(x, 32);
    return fmaf(sgn, x, p);
#endif
}
__device__ __forceinline__ __half2 bfly16_h2(__half2 x, __half2 sgn) {
#if __has_builtin(__builtin_amdgcn_permlane16_swap)
    uint2v r = __builtin_amdgcn_permlane16_swap(h2u(x), h2u(x), false, false);
    return __hfma2(u2h(r.y), sgn, u2h(r.x));
#else
    __half2 p = u2h((unsigned)__shfl_xor((int)h2u(x), 16));
    return __hfma2(x, sgn, p);
#endif
}
__device__ __forceinline__ __half2 bfly32_h2(__half2 x, __half2 sgn) {
#if __has_builtin(__builtin_amdgcn_permlane32_swap)
    uint2v r = __builtin_amdgcn_permlane32_swap(h2u(x), h2u(x), false, false);
    return __hfma2(u2h(r.y), sgn, u2h(r.x));
#else
    __half2 p = u2h((unsigned)__shfl_xor((int)h2u(x), 32));
    return __hfma2(x, sgn, p);
#endif
}

// ---------------- f32 WHT over 10 bits (4 reg bits + 6 lane bits) ----------------
// Entirely VALU: 3 DPP stages + xor4 DPP-pair + 2 permlane stages. No DS ops.
__device__ __forceinline__ void wht16_f32(float v[16], int lane) {
    #pragma unroll
    for (int s = 1; s < 16; s <<= 1)
        #pragma unroll
        for (int r = 0; r < 16; r++)
            if (!(r & s)) bf(v[r], v[r ^ s]);
    {   float sgn = (lane & 1) ? -1.0f : 1.0f;
        #pragma unroll
        for (int r = 0; r < 16; r++) { float p = dppf<0xB1>(v[r]); v[r] = fmaf(sgn, v[r], p); } }
    {   float sgn = (lane & 2) ? -1.0f : 1.0f;
        #pragma unroll
        for (int r = 0; r < 16; r++) { float p = dppf<0x4E>(v[r]); v[r] = fmaf(sgn, v[r], p); } }
    {   float sgn = (lane & 4) ? -1.0f : 1.0f;
        #pragma unroll
        for (int r = 0; r < 16; r++) { float p = xor4_f(v[r]); v[r] = fmaf(sgn, v[r], p); } }
    {   float sgn = (lane & 8) ? -1.0f : 1.0f;
        #pragma unroll
        for (int r = 0; r < 16; r++) { float p = dppf<0x128>(v[r]); v[r] = fmaf(sgn, v[r], p); } }
    {   float sgn = (lane & 16) ? -1.0f : 1.0f;
        #pragma unroll
        for (int r = 0; r < 16; r++) v[r] = bfly16_f(v[r], sgn); }
    {   float sgn = (lane & 32) ? -1.0f : 1.0f;
        #pragma unroll
        for (int r = 0; r < 16; r++) v[r] = bfly32_f(v[r], sgn); }
}

// ---------------- half2 (re,im)-packed WHT over 10 bits ----------------
__device__ __forceinline__ void wht16_h2(__half2 v[16], int lane) {
    #pragma unroll
    for (int s = 1; s < 16; s <<= 1)
        #pragma unroll
        for (int r = 0; r < 16; r++)
            if (!(r & s)) {
                __half2 t = __hadd2(v[r], v[r ^ s]);
                v[r ^ s]  = __hsub2(v[r], v[r ^ s]);
                v[r] = t;
            }
    {   __half2 sgn = __float2half2_rn((lane & 1) ? -1.0f : 1.0f);
        #pragma unroll
        for (int r = 0; r < 16; r++) { __half2 p = u2h(dppu<0xB1>(h2u(v[r]))); v[r] = __hfma2(v[r], sgn, p); } }
    {   __half2 sgn = __float2half2_rn((lane & 2) ? -1.0f : 1.0f);
        #pragma unroll
        for (int r = 0; r < 16; r++) { __half2 p = u2h(dppu<0x4E>(h2u(v[r]))); v[r] = __hfma2(v[r], sgn, p); } }
    {   __half2 sgn = __float2half2_rn((lane & 4) ? -1.0f : 1.0f);
        #pragma unroll
        for (int r = 0; r < 16; r++) { __half2 p = u2h(xor4_u(h2u(v[r]))); v[r] = __hfma2(v[r], sgn, p); } }
    {   __half2 sgn = __float2half2_rn((lane & 8) ? -1.0f : 1.0f);
        #pragma unroll
        for (int r = 0; r < 16; r++) { __half2 p = u2h(dppu<0x128>(h2u(v[r]))); v[r] = __hfma2(v[r], sgn, p); } }
    {   __half2 sgn = __float2half2_rn((lane & 16) ? -1.0f : 1.0f);
        #pragma unroll
        for (int r = 0; r < 16; r++) v[r] = bfly16_h2(v[r], sgn); }
    {   __half2 sgn = __float2half2_rn((lane & 32) ? -1.0f : 1.0f);
        #pragma unroll
        for (int r = 0; r < 16; r++) v[r] = bfly32_h2(v[r], sgn); }
}

// XOR-permute 4 words by elo (0..3), compile-time indices only
__device__ __forceinline__ void xorperm4(unsigned int a[4], int elo) {
    bool s0 = (elo & 1) != 0, s1 = (elo & 2) != 0;
    unsigned int t0 = s0 ? a[1] : a[0], t1 = s0 ? a[0] : a[1];
    unsigned int t2 = s0 ? a[3] : a[2], t3 = s0 ? a[2] : a[3];
    a[0] = s1 ? t2 : t0; a[1] = s1 ? t3 : t1;
    a[2] = s1 ? t0 : t2; a[3] = s1 ? t1 : t3;
}

// ================= Pass 1: f32 in -> low-10 WHT (f32 math) -> fp16 ws =================
// layout: element l = q*512 + lane*8 + s
__global__ __launch_bounds__(256, 4) void p1_kernel(const float* __restrict__ xr,
                                                    const float* __restrict__ xi,
                                                    __half* __restrict__ ws) {
    const int tid = threadIdx.x, lane = tid & 63, w = tid >> 6;
    const int rt = blockIdx.x * 4 + w;              // (batch*1024 + h) in [0,16384)
    const float* re = xr + (size_t)rt * 1024;
    const float* im = xi + (size_t)rt * 1024;
    float vr[16], vi[16];
    #pragma unroll
    for (int q = 0; q < 2; q++) {
        const int base = q * 512 + lane * 8;
        float4 a0 = *(const float4*)(re + base);
        float4 a1 = *(const float4*)(re + base + 4);
        float4 b0 = *(const float4*)(im + base);
        float4 b1 = *(const float4*)(im + base + 4);
        vr[q*8+0]=a0.x*0.03125f; vr[q*8+1]=a0.y*0.03125f; vr[q*8+2]=a0.z*0.03125f; vr[q*8+3]=a0.w*0.03125f;
        vr[q*8+4]=a1.x*0.03125f; vr[q*8+5]=a1.y*0.03125f; vr[q*8+6]=a1.z*0.03125f; vr[q*8+7]=a1.w*0.03125f;
        vi[q*8+0]=b0.x*0.03125f; vi[q*8+1]=b0.y*0.03125f; vi[q*8+2]=b0.z*0.03125f; vi[q*8+3]=b0.w*0.03125f;
        vi[q*8+4]=b1.x*0.03125f; vi[q*8+5]=b1.y*0.03125f; vi[q*8+6]=b1.z*0.03125f; vi[q*8+7]=b1.w*0.03125f;
    }
    wht16_f32(vr, lane);
    wht16_f32(vi, lane);
    __half* wr = ws + (size_t)rt * 1024;
    __half* wi = ws + (size_t)16 * DIMN + (size_t)rt * 1024;
    #pragma unroll
    for (int q = 0; q < 2; q++) {
        const int base = q * 512 + lane * 8;
        uint4 pr, pi;
        pr.x = h2u(__floats2half2_rn(vr[q*8+0], vr[q*8+1]));
        pr.y = h2u(__floats2half2_rn(vr[q*8+2], vr[q*8+3]));
        pr.z = h2u(__floats2half2_rn(vr[q*8+4], vr[q*8+5]));
        pr.w = h2u(__floats2half2_rn(vr[q*8+6], vr[q*8+7]));
        pi.x = h2u(__floats2half2_rn(vi[q*8+0], vi[q*8+1]));
        pi.y = h2u(__floats2half2_rn(vi[q*8+2], vi[q*8+3]));
        pi.z = h2u(__floats2half2_rn(vi[q*8+4], vi[q*8+5]));
        pi.w = h2u(__floats2half2_rn(vi[q*8+6], vi[q*8+7]));
        *(uint4*)(wr + base) = pr;
        *(uint4*)(wi + base) = pi;
    }
}

// ================= Pass 3: fp16 ws -> low-10 WHT (f32 math) -> f32 out =================
__global__ __launch_bounds__(256, 4) void p3_kernel(const __half* __restrict__ ws,
                                                    float* __restrict__ out) {
    const int tid = threadIdx.x, lane = tid & 63, w = tid >> 6;
    const int rt = blockIdx.x * 4 + w;
    const __half* wr = ws + (size_t)rt * 1024;
    const __half* wi = ws + (size_t)16 * DIMN + (size_t)rt * 1024;
    float vr[16], vi[16];
    #pragma unroll
    for (int q = 0; q < 2; q++) {
        const int base = q * 512 + lane * 8;
        uint4 pr = *(const uint4*)(wr + base);
        uint4 pi = *(const uint4*)(wi + base);
        __half2 a0=u2h(pr.x), a1=u2h(pr.y), a2=u2h(pr.z), a3=u2h(pr.w);
        __half2 b0=u2h(pi.x), b1=u2h(pi.y), b2=u2h(pi.z), b3=u2h(pi.w);
        vr[q*8+0]=__low2float(a0)*0.03125f; vr[q*8+1]=__high2float(a0)*0.03125f;
        vr[q*8+2]=__low2float(a1)*0.03125f; vr[q*8+3]=__high2float(a1)*0.03125f;
        vr[q*8+4]=__low2float(a2)*0.03125f; vr[q*8+5]=__high2float(a2)*0.03125f;
        vr[q*8+6]=__low2float(a3)*0.03125f; vr[q*8+7]=__high2float(a3)*0.03125f;
        vi[q*8+0]=__low2float(b0)*0.03125f; vi[q*8+1]=__high2float(b0)*0.03125f;
        vi[q*8+2]=__low2float(b1)*0.03125f; vi[q*8+3]=__high2float(b1)*0.03125f;
        vi[q*8+4]=__low2float(b2)*0.03125f; vi[q*8+5]=__high2float(b2)*0.03125f;
        vi[q*8+6]=__low2float(b3)*0.03125f; vi[q*8+7]=__high2float(b3)*0.03125f;
    }
    wht16_f32(vr, lane);
    wht16_f32(vi, lane);
    float* outr = out + (size_t)rt * 1024;
    float* outi = out + (size_t)16 * DIMN + (size_t)rt * 1024;
    #pragma unroll
    for (int q = 0; q < 2; q++) {
        const int base = q * 512 + lane * 8;
        *(float4*)(outr + base)     = make_float4(vr[q*8+0], vr[q*8+1], vr[q*8+2], vr[q*8+3]);
        *(float4*)(outr + base + 4) = make_float4(vr[q*8+4], vr[q*8+5], vr[q*8+6], vr[q*8+7]);
        *(float4*)(outi + base)     = make_float4(vi[q*8+0], vi[q*8+1], vi[q*8+2], vi[q*8+3]);
        *(float4*)(outi + base + 4) = make_float4(vi[q*8+4], vi[q*8+5], vi[q*8+6], vi[q*8+7]);
    }
}

// ================= Pass 2: high-10 WHT + rotate + high-10 WHT, half2(re,im) packed =================
// Tile: [1024 h][8 cols] of half2 = 32 KiB LDS. 512 threads, wave w owns column w.
__global__ __launch_bounds__(512, 4) void p2_kernel(__half* __restrict__ ws,
                                                    const float* __restrict__ tptr) {
    __shared__ unsigned int tile[1024][8];
    const int tid = threadIdx.x, lane = tid & 63, w = tid >> 6;

    // XCD-chunked bijective swizzle (2048 % 8 == 0)
    int wg  = blockIdx.x;
    int swz = (wg & 7) * 256 + (wg >> 3);
    const int b  = swz >> 7;           // batch 0..15
    const int g  = swz & 127;          // column group 0..127
    const int c0 = g * 8;
    const float tval = tptr[0];

    // ---- rotation coefficients (depend only on t and lane/col popcounts):
    // computed FIRST so the sincos chain overlaps the staging loads below.
    const int l = c0 + w;
    const int pbase = __popc(lane) + __popc(l);
    __half2 c2k[5], s2k[5];
    #pragma unroll
    for (int k = 0; k < 5; k++) {
        float ang = tval * (float)(20 - 2 * (pbase + k));
        float s, c;
        __sincosf(ang, &s, &c);
        c2k[k] = __float2half2_rn(c * 0.03125f);                     // (c', c')
        s2k[k] = __halves2half2(__float2half(s * 0.03125f),
                                __float2half(-s * 0.03125f));        // (s', -s')
    }

    __half* re = ws + (size_t)b * DIMN + c0;
    __half* im = ws + (size_t)16 * DIMN + (size_t)b * DIMN + c0;

    // ---- stage-in: interleave (re,im) -> half2 words, swizzled LDS ----
    #pragma unroll
    for (int it = 0; it < 2; it++) {
        int h = it * 512 + tid;
        uint4 ra = *(const uint4*)(re + (size_t)h * 1024);
        uint4 ia = *(const uint4*)(im + (size_t)h * 1024);
        unsigned int g0[4], g1[4];
        g0[0] = (ra.x & 0xFFFFu) | (ia.x << 16);
        g0[1] = (ra.x >> 16)     | (ia.x & 0xFFFF0000u);
        g0[2] = (ra.y & 0xFFFFu) | (ia.y << 16);
        g0[3] = (ra.y >> 16)     | (ia.y & 0xFFFF0000u);
        g1[0] = (ra.z & 0xFFFFu) | (ia.z << 16);
        g1[1] = (ra.z >> 16)     | (ia.z & 0xFFFF0000u);
        g1[2] = (ra.w & 0xFFFFu) | (ia.w << 16);
        g1[3] = (ra.w >> 16)     | (ia.w & 0xFFFF0000u);
        int e = (h >> 2) & 7;
        xorperm4(g0, e & 3);
        xorperm4(g1, e & 3);
        int ehi = (e >> 2) & 1;
        *(uint4*)&tile[h][ehi ? 4 : 0] = make_uint4(g0[0], g0[1], g0[2], g0[3]);
        *(uint4*)&tile[h][ehi ? 0 : 4] = make_uint4(g1[0], g1[1], g1[2], g1[3]);
    }
    __syncthreads();

    // ---- LDS -> regs: wave w's logical column w (conflict-free) ----
    const int ecol = w ^ ((lane >> 2) & 7);
    const __half2 sc = __float2half2_rn(0.03125f);
    __half2 v[16];
    #pragma unroll
    for (int r = 0; r < 16; r++)
        v[r] = __hmul2(u2h(tile[r * 64 + lane][ecol]), sc);   // pre-scale 2^-5

    // ---- WHT #1 (high 10 bits) ----
    wht16_h2(v, lane);

    // ---- rotation in packed fp16: v' = c2*v + s2*swap16(v) ----
    #pragma unroll
    for (int r = 0; r < 16; r++) {
        const int pr = __popc(r);
        unsigned int u = h2u(v[r]);
        __half2 vswap = u2h((u >> 16) | (u << 16));           // (xi, xr)
        v[r] = __hfma2(c2k[pr], v[r], __hmul2(s2k[pr], vswap));
    }

    // ---- WHT #2 (high 10 bits) ----
    wht16_h2(v, lane);

    // ---- regs -> LDS (own column) ----
    #pragma unroll
    for (int r = 0; r < 16; r++)
        tile[r * 64 + lane][ecol] = h2u(v[r]);
    __syncthreads();

    // ---- stage-out: inverse of stage-in ----
    #pragma unroll
    for (int it = 0; it < 2; it++) {
        int h = it * 512 + tid;
        int e = (h >> 2) & 7;
        int ehi = (e >> 2) & 1;
        uint4 u0 = *(const uint4*)&tile[h][ehi ? 4 : 0];
        uint4 u1 = *(const uint4*)&tile[h][ehi ? 0 : 4];
        unsigned int g0[4] = {u0.x, u0.y, u0.z, u0.w};
        unsigned int g1[4] = {u1.x, u1.y, u1.z, u1.w};
        xorperm4(g0, e & 3);
        xorperm4(g1, e & 3);
        uint4 ra, ia;
        ra.x = (g0[0] & 0xFFFFu) | (g0[1] << 16);
        ia.x = (g0[0] >> 16)     | (g0[1] & 0xFFFF0000u);
        ra.y = (g0[2] & 0xFFFFu) | (g0[3] << 16);
        ia.y = (g0[2] >> 16)     | (g0[3] & 0xFFFF0000u);
        ra.z = (g1[0] & 0xFFFFu) | (g1[1] << 16);
        ia.z = (g1[0] >> 16)     | (g1[1] & 0xFFFF0000u);
        ra.w = (g1[2] & 0xFFFFu) | (g1[3] << 16);
        ia.w = (g1[2] >> 16)     | (g1[3] & 0xFFFF0000u);
        *(uint4*)(re + (size_t)h * 1024) = ra;
        *(uint4*)(im + (size_t)h * 1024) = ia;
    }
}

// ================= fp32 fallback (used only if ws too small) =================
__device__ __forceinline__ void wht10_f4(float4 v[4], int lane) {
    #pragma unroll
    for (int r = 0; r < 4; r++) {
        bf(v[r].x, v[r].y); bf(v[r].z, v[r].w);
        bf(v[r].x, v[r].z); bf(v[r].y, v[r].w);
    }
    #pragma unroll
    for (int m = 1; m <= 32; m <<= 1) {
        float sgn = (lane & m) ? -1.0f : 1.0f;
        #pragma unroll
        for (int r = 0; r < 4; r++) {
            float px = __shfl_xor(v[r].x, m), py = __shfl_xor(v[r].y, m);
            float pz = __shfl_xor(v[r].z, m), pw = __shfl_xor(v[r].w, m);
            v[r].x = fmaf(sgn, v[r].x, px); v[r].y = fmaf(sgn, v[r].y, py);
            v[r].z = fmaf(sgn, v[r].z, pz); v[r].w = fmaf(sgn, v[r].w, pw);
        }
    }
    bf(v[0].x, v[1].x); bf(v[0].y, v[1].y); bf(v[0].z, v[1].z); bf(v[0].w, v[1].w);
    bf(v[2].x, v[3].x); bf(v[2].y, v[3].y); bf(v[2].z, v[3].z); bf(v[2].w, v[3].w);
    bf(v[0].x, v[2].x); bf(v[0].y, v[2].y); bf(v[0].z, v[2].z); bf(v[0].w, v[2].w);
    bf(v[1].x, v[3].x); bf(v[1].y, v[3].y); bf(v[1].z, v[3].z); bf(v[1].w, v[3].w);
}

__global__ __launch_bounds__(256) void pass13_kernel(const float* __restrict__ srcA,
                                                     const float* __restrict__ srcB,
                                                     float* __restrict__ dst) {
    const int tid = threadIdx.x, lane = tid & 63, w = tid >> 6;
    const int rt0 = blockIdx.x * 16 + w * 4;
    const float* src = (rt0 < 16384) ? (srcA + (size_t)rt0 * 1024)
                                     : (srcB + (size_t)(rt0 - 16384) * 1024);
    float* d = dst + (size_t)rt0 * 1024;
    float4 v[4][4];
    #pragma unroll
    for (int rr = 0; rr < 4; rr++)
        #pragma unroll
        for (int r = 0; r < 4; r++)
            v[rr][r] = *(const float4*)(src + rr * 1024 + r * 256 + lane * 4);
    #pragma unroll
    for (int rr = 0; rr < 4; rr++) {
        wht10_f4(v[rr], lane);
        #pragma unroll
        for (int r = 0; r < 4; r++) {
            float4 o;
            o.x = v[rr][r].x * 0.03125f; o.y = v[rr][r].y * 0.03125f;
            o.z = v[rr][r].z * 0.03125f; o.w = v[rr][r].w * 0.03125f;
            *(float4*)(d + rr * 1024 + r * 256 + lane * 4) = o;
        }
    }
}

__global__ __launch_bounds__(256) void pass2_kernel(float* __restrict__ out,
                                                    const float* __restrict__ tptr) {
    __shared__ __align__(16) float tile[2][1024][8];
    const int tid = threadIdx.x, lane = tid & 63, w = tid >> 6;
    int wg = blockIdx.x;
    int swz = (wg & 7) * 256 + (wg >> 3);
    const int b = swz >> 7, g = swz & 127;
    const int c0 = g * 8;
    const float tval = tptr[0];
    float* baseR = out + (size_t)b * DIMN;
    float* baseI = out + (size_t)16 * DIMN + (size_t)b * DIMN;
    float4 tmp[2][8];
    #pragma unroll
    for (int comp = 0; comp < 2; comp++) {
        const float* src = comp ? baseI : baseR;
        #pragma unroll
        for (int it = 0; it < 8; it++) {
            int f4id = it * 256 + tid;
            int h = f4id >> 1, q = f4id & 1;
            tmp[comp][it] = *(const float4*)(src + (size_t)h * 1024 + c0 + q * 4);
        }
    }
    #pragma unroll
    for (int comp = 0; comp < 2; comp++) {
        #pragma unroll
        for (int it = 0; it < 8; it++) {
            int f4id = it * 256 + tid;
            int h = f4id >> 1, q = f4id & 1;
            int e = (h >> 2) & 7, elo = e & 3;
            float4 val = tmp[comp][it];
            bool s0 = (elo & 1) != 0;
            float x1 = s0 ? val.y : val.x, y1 = s0 ? val.x : val.y;
            float z1 = s0 ? val.w : val.z, w1 = s0 ? val.z : val.w;
            bool s1 = (elo & 2) != 0;
            float x2 = s1 ? z1 : x1, y2 = s1 ? w1 : y1;
            float z2 = s1 ? x1 : z1, w2 = s1 ? y1 : w1;
            int qp = q ^ (e >> 2);
            *(float4*)&tile[comp][h][qp * 4] = make_float4(x2, y2, z2, w2);
        }
    }
    __syncthreads();
    float vr[2][16], vi[2][16];
    #pragma unroll
    for (int r = 0; r < 16; r++) {
        int h = r * 64 + lane;
        int e = (lane >> 2) & 7;
        #pragma unroll
        for (int cc = 0; cc < 2; cc++) {
            int cp = (2 * w + cc) ^ e;
            vr[cc][r] = tile[0][h][cp];
            vi[cc][r] = tile[1][h][cp];
        }
    }
    const int pcl = __popc(lane);
    #pragma unroll
    for (int cc = 0; cc < 2; cc++) {
        wht16_f32(vr[cc], lane);
        wht16_f32(vi[cc], lane);
        const int cg = c0 + 2 * w + cc;
        const int pbase = pcl + __popc(cg);
        float csk[5], snk[5];
        #pragma unroll
        for (int k = 0; k < 5; k++) {
            float ang = tval * (float)(20 - 2 * (pbase + k));
            __sincosf(ang, &snk[k], &csk[k]);
        }
        #pragma unroll
        for (int r = 0; r < 16; r++) {
            const int pr = __popc(r);
            float cv = csk[pr], sv = snk[pr];
            float xr = vr[cc][r] * 0.03125f, xi = vi[cc][r] * 0.03125f;
            vr[cc][r] = fmaf(cv, xr, sv * xi);
            vi[cc][r] = fmaf(cv, xi, -sv * xr);
        }
        wht16_f32(vr[cc], lane);
        wht16_f32(vi[cc], lane);
    }
    #pragma unroll
    for (int r = 0; r < 16; r++) {
        int h = r * 64 + lane;
        int e = (lane >> 2) & 7;
        #pragma unroll
        for (int cc = 0; cc < 2; cc++) {
            int cp = (2 * w + cc) ^ e;
            tile[0][h][cp] = vr[cc][r] * 0.03125f;
            tile[1][h][cp] = vi[cc][r] * 0.03125f;
        }
    }
    __syncthreads();
    #pragma unroll
    for (int comp = 0; comp < 2; comp++) {
        float* dstg = comp ? baseI : baseR;
        #pragma unroll
        for (int it = 0; it < 8; it++) {
            int f4id = it * 256 + tid;
            int h = f4id >> 1, q = f4id & 1;
            int e = (h >> 2) & 7, elo = e & 3;
            int qp = q ^ (e >> 2);
            float4 sv = *(const float4*)&tile[comp][h][qp * 4];
            bool s0 = (elo & 1) != 0;
            float x1 = s0 ? sv.y : sv.x, y1 = s0 ? sv.x : sv.y;
            float z1 = s0 ? sv.w : sv.z, w1 = s0 ? sv.z : sv.w;
            bool s1 = (elo & 2) != 0;
            float x2 = s1 ? z1 : x1, y2 = s1 ? w1 : y1;
            float z2 = s1 ? x1 : z1, w2 = s1 ? y1 : w1;
            *(float4*)(dstg + (size_t)h * 1024 + c0 + q * 4) = make_float4(x2, y2, z2, w2);
        }
    }
}

extern "C" void kernel_launch(void* const* d_in, const int* in_sizes, int n_in,
                              void* d_out, int out_size, void* d_ws, size_t ws_size,
                              hipStream_t stream) {
    const float* xr = (const float*)d_in[0];
    const float* xi = (const float*)d_in[1];
    const float* t  = (const float*)d_in[2];
    float* out = (float*)d_out;

    const size_t need = (size_t)2 * 16 * DIMN * sizeof(__half);  // 64 MiB
    if (ws_size >= need) {
        __half* ws = (__half*)d_ws;
        p1_kernel<<<4096, 256, 0, stream>>>(xr, xi, ws);
        p2_kernel<<<2048, 512, 0, stream>>>(ws, t);
        p3_kernel<<<4096, 256, 0, stream>>>(ws, out);
    } else {
        pass13_kernel<<<2048, 256, 0, stream>>>(xr, xi, out);
        pass2_kernel<<<2048, 256, 0, stream>>>(out, t);
        pass13_kernel<<<2048, 256, 0, stream>>>(out, out + (size_t)16 * DIMN, out);
    }
}

// Round 8
// 114.170 us; speedup vs baseline: 1.5701x; 1.0386x over previous
//
#include <hip/hip_runtime.h>
#include <hip/hip_fp16.h>
#include <math.h>

#define DIMN (1 << 20)   // 2^20 per batch row
// d_out: [2][16][DIMN] f32.  d_ws (fp16 path): [2][16][DIMN] __half.

typedef unsigned int uint2v __attribute__((ext_vector_type(2)));

// ---------------- bit-cast helpers ----------------
__device__ __forceinline__ unsigned int h2u(__half2 v){ union{__half2 h; unsigned int u;} x; x.h=v; return x.u; }
__device__ __forceinline__ __half2 u2h(unsigned int v){ union{unsigned int u; __half2 h;} x; x.u=v; return x.h; }

__device__ __forceinline__ void bf(float& a, float& b) { float s = a + b; b = a - b; a = s; }

// ---------------- DPP lane-exchange (VALU pipe, not DS) ----------------
template<int CTRL>
__device__ __forceinline__ float dppf(float x) {
    return __int_as_float(__builtin_amdgcn_mov_dpp(__float_as_int(x), CTRL, 0xF, 0xF, true));
}
template<int CTRL>
__device__ __forceinline__ unsigned int dppu(unsigned int x) {
    return (unsigned int)__builtin_amdgcn_mov_dpp((int)x, CTRL, 0xF, 0xF, true);
}
__device__ __forceinline__ float xor4_f(float x) { return dppf<0x1B>(dppf<0x141>(x)); }
__device__ __forceinline__ unsigned int xor4_u(unsigned int x) { return dppu<0x1B>(dppu<0x141>(x)); }

// ---------------- permlane swap butterflies (VALU pipe) ----------------
__device__ __forceinline__ float bfly16_f(float x, float sgn) {
#if __has_builtin(__builtin_amdgcn_permlane16_swap)
    uint2v r = __builtin_amdgcn_permlane16_swap(__float_as_uint(x), __float_as_uint(x), false, false);
    return fmaf(sgn, __uint_as_float(r.y), __uint_as_float(r.x));
#else
    float p = __shfl_xor(x, 16);
    return fmaf(sgn, x, p);
#endif
}
__device__ __forceinline__ float bfly32_f(float x, float sgn) {
#if __has_builtin(__builtin_amdgcn_permlane32_swap)
    uint2v r = __builtin_amdgcn_permlane32_swap(__float_as_uint(x), __float_as_uint(x), false, false);
    return fmaf(sgn, __uint_as_float(r.y), __uint_as_float(r.x));
#else
    float p = __shfl_xor(x, 32);
    return fmaf(sgn, x, p);
#endif
}
__device__ __forceinline__ __half2 bfly16_h2(__half2 x, __half2 sgn) {
#if __has_builtin(__builtin_amdgcn_permlane16_swap)
    uint2v r = __builtin_amdgcn_permlane16_swap(h2u(x), h2u(x), false, false);
    return __hfma2(u2h(r.y), sgn, u2h(r.x));
#else
    __half2 p = u2h((unsigned)__shfl_xor((int)h2u(x), 16));
    return __hfma2(x, sgn, p);
#endif
}
__device__ __forceinline__ __half2 bfly32_h2(__half2 x, __half2 sgn) {
#if __has_builtin(__builtin_amdgcn_permlane32_swap)
    uint2v r = __builtin_amdgcn_permlane32_swap(h2u(x), h2u(x), false, false);
    return __hfma2(u2h(r.y), sgn, u2h(r.x));
#else
    __half2 p = u2h((unsigned)__shfl_xor((int)h2u(x), 32));
    return __hfma2(x, sgn, p);
#endif
}

// ---------------- f32 WHT over 10 bits (all-VALU lane exchange) ----------------
__device__ __forceinline__ void wht16_f32(float v[16], int lane) {
    #pragma unroll
    for (int s = 1; s < 16; s <<= 1)
        #pragma unroll
        for (int r = 0; r < 16; r++)
            if (!(r & s)) bf(v[r], v[r ^ s]);
    {   float sgn = (lane & 1) ? -1.0f : 1.0f;
        #pragma unroll
        for (int r = 0; r < 16; r++) { float p = dppf<0xB1>(v[r]); v[r] = fmaf(sgn, v[r], p); } }
    {   float sgn = (lane & 2) ? -1.0f : 1.0f;
        #pragma unroll
        for (int r = 0; r < 16; r++) { float p = dppf<0x4E>(v[r]); v[r] = fmaf(sgn, v[r], p); } }
    {   float sgn = (lane & 4) ? -1.0f : 1.0f;
        #pragma unroll
        for (int r = 0; r < 16; r++) { float p = xor4_f(v[r]); v[r] = fmaf(sgn, v[r], p); } }
    {   float sgn = (lane & 8) ? -1.0f : 1.0f;
        #pragma unroll
        for (int r = 0; r < 16; r++) { float p = dppf<0x128>(v[r]); v[r] = fmaf(sgn, v[r], p); } }
    {   float sgn = (lane & 16) ? -1.0f : 1.0f;
        #pragma unroll
        for (int r = 0; r < 16; r++) v[r] = bfly16_f(v[r], sgn); }
    {   float sgn = (lane & 32) ? -1.0f : 1.0f;
        #pragma unroll
        for (int r = 0; r < 16; r++) v[r] = bfly32_f(v[r], sgn); }
}

// ---------------- half2 (re,im)-packed WHT over 10 bits ----------------
__device__ __forceinline__ void wht16_h2(__half2 v[16], int lane) {
    #pragma unroll
    for (int s = 1; s < 16; s <<= 1)
        #pragma unroll
        for (int r = 0; r < 16; r++)
            if (!(r & s)) {
                __half2 t = __hadd2(v[r], v[r ^ s]);
                v[r ^ s]  = __hsub2(v[r], v[r ^ s]);
                v[r] = t;
            }
    {   __half2 sgn = __float2half2_rn((lane & 1) ? -1.0f : 1.0f);
        #pragma unroll
        for (int r = 0; r < 16; r++) { __half2 p = u2h(dppu<0xB1>(h2u(v[r]))); v[r] = __hfma2(v[r], sgn, p); } }
    {   __half2 sgn = __float2half2_rn((lane & 2) ? -1.0f : 1.0f);
        #pragma unroll
        for (int r = 0; r < 16; r++) { __half2 p = u2h(dppu<0x4E>(h2u(v[r]))); v[r] = __hfma2(v[r], sgn, p); } }
    {   __half2 sgn = __float2half2_rn((lane & 4) ? -1.0f : 1.0f);
        #pragma unroll
        for (int r = 0; r < 16; r++) { __half2 p = u2h(xor4_u(h2u(v[r]))); v[r] = __hfma2(v[r], sgn, p); } }
    {   __half2 sgn = __float2half2_rn((lane & 8) ? -1.0f : 1.0f);
        #pragma unroll
        for (int r = 0; r < 16; r++) { __half2 p = u2h(dppu<0x128>(h2u(v[r]))); v[r] = __hfma2(v[r], sgn, p); } }
    {   __half2 sgn = __float2half2_rn((lane & 16) ? -1.0f : 1.0f);
        #pragma unroll
        for (int r = 0; r < 16; r++) v[r] = bfly16_h2(v[r], sgn); }
    {   __half2 sgn = __float2half2_rn((lane & 32) ? -1.0f : 1.0f);
        #pragma unroll
        for (int r = 0; r < 16; r++) v[r] = bfly32_h2(v[r], sgn); }
}

// XOR-permute 8 words by m (0..7): a'[j] = a[j ^ m], compile-time indices only
__device__ __forceinline__ void xorperm8(unsigned int a[8], int m) {
    bool s0 = (m & 1) != 0, s1 = (m & 2) != 0, s2 = (m & 4) != 0;
    unsigned int b0 = s0 ? a[1] : a[0], b1 = s0 ? a[0] : a[1];
    unsigned int b2 = s0 ? a[3] : a[2], b3 = s0 ? a[2] : a[3];
    unsigned int b4 = s0 ? a[5] : a[4], b5 = s0 ? a[4] : a[5];
    unsigned int b6 = s0 ? a[7] : a[6], b7 = s0 ? a[6] : a[7];
    unsigned int c0 = s1 ? b2 : b0, c1 = s1 ? b3 : b1;
    unsigned int c2 = s1 ? b0 : b2, c3 = s1 ? b1 : b3;
    unsigned int c4 = s1 ? b6 : b4, c5 = s1 ? b7 : b5;
    unsigned int c6 = s1 ? b4 : b6, c7 = s1 ? b5 : b7;
    a[0] = s2 ? c4 : c0; a[1] = s2 ? c5 : c1;
    a[2] = s2 ? c6 : c2; a[3] = s2 ? c7 : c3;
    a[4] = s2 ? c0 : c4; a[5] = s2 ? c1 : c5;
    a[6] = s2 ? c2 : c6; a[7] = s2 ? c3 : c7;
}

// ================= Pass 1: f32 in -> low-10 WHT (f32 math) -> fp16 ws =================
__global__ __launch_bounds__(256, 4) void p1_kernel(const float* __restrict__ xr,
                                                    const float* __restrict__ xi,
                                                    __half* __restrict__ ws) {
    const int tid = threadIdx.x, lane = tid & 63, w = tid >> 6;
    const int rt = blockIdx.x * 4 + w;
    const float* re = xr + (size_t)rt * 1024;
    const float* im = xi + (size_t)rt * 1024;
    float vr[16], vi[16];
    #pragma unroll
    for (int q = 0; q < 2; q++) {
        const int base = q * 512 + lane * 8;
        float4 a0 = *(const float4*)(re + base);
        float4 a1 = *(const float4*)(re + base + 4);
        float4 b0 = *(const float4*)(im + base);
        float4 b1 = *(const float4*)(im + base + 4);
        vr[q*8+0]=a0.x*0.03125f; vr[q*8+1]=a0.y*0.03125f; vr[q*8+2]=a0.z*0.03125f; vr[q*8+3]=a0.w*0.03125f;
        vr[q*8+4]=a1.x*0.03125f; vr[q*8+5]=a1.y*0.03125f; vr[q*8+6]=a1.z*0.03125f; vr[q*8+7]=a1.w*0.03125f;
        vi[q*8+0]=b0.x*0.03125f; vi[q*8+1]=b0.y*0.03125f; vi[q*8+2]=b0.z*0.03125f; vi[q*8+3]=b0.w*0.03125f;
        vi[q*8+4]=b1.x*0.03125f; vi[q*8+5]=b1.y*0.03125f; vi[q*8+6]=b1.z*0.03125f; vi[q*8+7]=b1.w*0.03125f;
    }
    wht16_f32(vr, lane);
    wht16_f32(vi, lane);
    __half* wr = ws + (size_t)rt * 1024;
    __half* wi = ws + (size_t)16 * DIMN + (size_t)rt * 1024;
    #pragma unroll
    for (int q = 0; q < 2; q++) {
        const int base = q * 512 + lane * 8;
        uint4 pr, pi;
        pr.x = h2u(__floats2half2_rn(vr[q*8+0], vr[q*8+1]));
        pr.y = h2u(__floats2half2_rn(vr[q*8+2], vr[q*8+3]));
        pr.z = h2u(__floats2half2_rn(vr[q*8+4], vr[q*8+5]));
        pr.w = h2u(__floats2half2_rn(vr[q*8+6], vr[q*8+7]));
        pi.x = h2u(__floats2half2_rn(vi[q*8+0], vi[q*8+1]));
        pi.y = h2u(__floats2half2_rn(vi[q*8+2], vi[q*8+3]));
        pi.z = h2u(__floats2half2_rn(vi[q*8+4], vi[q*8+5]));
        pi.w = h2u(__floats2half2_rn(vi[q*8+6], vi[q*8+7]));
        *(uint4*)(wr + base) = pr;
        *(uint4*)(wi + base) = pi;
    }
}

// ================= Pass 3: fp16 ws -> low-10 WHT (f32 math) -> f32 out =================
__global__ __launch_bounds__(256, 4) void p3_kernel(const __half* __restrict__ ws,
                                                    float* __restrict__ out) {
    const int tid = threadIdx.x, lane = tid & 63, w = tid >> 6;
    const int rt = blockIdx.x * 4 + w;
    const __half* wr = ws + (size_t)rt * 1024;
    const __half* wi = ws + (size_t)16 * DIMN + (size_t)rt * 1024;
    float vr[16], vi[16];
    #pragma unroll
    for (int q = 0; q < 2; q++) {
        const int base = q * 512 + lane * 8;
        uint4 pr = *(const uint4*)(wr + base);
        uint4 pi = *(const uint4*)(wi + base);
        __half2 a0=u2h(pr.x), a1=u2h(pr.y), a2=u2h(pr.z), a3=u2h(pr.w);
        __half2 b0=u2h(pi.x), b1=u2h(pi.y), b2=u2h(pi.z), b3=u2h(pi.w);
        vr[q*8+0]=__low2float(a0)*0.03125f; vr[q*8+1]=__high2float(a0)*0.03125f;
        vr[q*8+2]=__low2float(a1)*0.03125f; vr[q*8+3]=__high2float(a1)*0.03125f;
        vr[q*8+4]=__low2float(a2)*0.03125f; vr[q*8+5]=__high2float(a2)*0.03125f;
        vr[q*8+6]=__low2float(a3)*0.03125f; vr[q*8+7]=__high2float(a3)*0.03125f;
        vi[q*8+0]=__low2float(b0)*0.03125f; vi[q*8+1]=__high2float(b0)*0.03125f;
        vi[q*8+2]=__low2float(b1)*0.03125f; vi[q*8+3]=__high2float(b1)*0.03125f;
        vi[q*8+4]=__low2float(b2)*0.03125f; vi[q*8+5]=__high2float(b2)*0.03125f;
        vi[q*8+6]=__low2float(b3)*0.03125f; vi[q*8+7]=__high2float(b3)*0.03125f;
    }
    wht16_f32(vr, lane);
    wht16_f32(vi, lane);
    float* outr = out + (size_t)rt * 1024;
    float* outi = out + (size_t)16 * DIMN + (size_t)rt * 1024;
    #pragma unroll
    for (int q = 0; q < 2; q++) {
        const int base = q * 512 + lane * 8;
        *(float4*)(outr + base)     = make_float4(vr[q*8+0], vr[q*8+1], vr[q*8+2], vr[q*8+3]);
        *(float4*)(outr + base + 4) = make_float4(vr[q*8+4], vr[q*8+5], vr[q*8+6], vr[q*8+7]);
        *(float4*)(outi + base)     = make_float4(vi[q*8+0], vi[q*8+1], vi[q*8+2], vi[q*8+3]);
        *(float4*)(outi + base + 4) = make_float4(vi[q*8+4], vi[q*8+5], vi[q*8+6], vi[q*8+7]);
    }
}

// ================= Pass 2: high-10 WHT + rotate + high-10 WHT =================
// Tile: [1024 h][16 cols] half2 = 64 KiB LDS. 512 threads; wave w owns logical
// columns {w, w+8}. Physical col = logical col ^ ((h>>2)&15): runs of 8
// preserved via register-side xorperm8 + run-base XOR (e&8).
// Stage: item f = (h,q), adjacent lanes share a row -> 32 B contiguous.
__global__ __launch_bounds__(512, 4) void p2_kernel(__half* __restrict__ ws,
                                                    const float* __restrict__ tptr) {
    __shared__ unsigned int tile[1024][16];
    const int tid = threadIdx.x, lane = tid & 63, w = tid >> 6;

    // XCD-chunked bijective swizzle (1024 % 8 == 0)
    int wg  = blockIdx.x;
    int swz = (wg & 7) * 128 + (wg >> 3);
    const int b  = swz >> 6;           // batch 0..15
    const int g  = swz & 63;           // column group 0..63
    const int c0 = g * 16;
    const float tval = tptr[0];

    // Rotation coefficients: l0 = c0+w (k=0..4), l1 = c0+w+8 (popc+1 -> k=1..5).
    const int pbase = __popc(lane) + __popc(c0 + w);
    __half2 c2k[6], s2k[6];
    #pragma unroll
    for (int k = 0; k < 6; k++) {
        float ang = tval * (float)(20 - 2 * (pbase + k));
        float s, c;
        __sincosf(ang, &s, &c);
        c2k[k] = __float2half2_rn(c * 0.03125f);                 // (c', c')
        s2k[k] = __halves2half2(__float2half(s * 0.03125f),
                                __float2half(-s * 0.03125f));    // (s', -s')
    }

    __half* re = ws + (size_t)b * DIMN + c0;
    __half* im = ws + (size_t)16 * DIMN + (size_t)b * DIMN + c0;

    // ---- stage-in: item f=(h,q); 1024 rows x 2 q-halves over 4 iters ----
    #pragma unroll
    for (int it = 0; it < 4; it++) {
        int f = it * 512 + tid;                // 0..2047
        int h = f >> 1, q = f & 1;
        uint4 ra = *(const uint4*)(re + (size_t)h * 1024 + q * 8);
        uint4 ia = *(const uint4*)(im + (size_t)h * 1024 + q * 8);
        unsigned int w8[8];
        w8[0] = (ra.x & 0xFFFFu) | (ia.x << 16);
        w8[1] = (ra.x >> 16)     | (ia.x & 0xFFFF0000u);
        w8[2] = (ra.y & 0xFFFFu) | (ia.y << 16);
        w8[3] = (ra.y >> 16)     | (ia.y & 0xFFFF0000u);
        w8[4] = (ra.z & 0xFFFFu) | (ia.z << 16);
        w8[5] = (ra.z >> 16)     | (ia.z & 0xFFFF0000u);
        w8[6] = (ra.w & 0xFFFFu) | (ia.w << 16);
        w8[7] = (ra.w >> 16)     | (ia.w & 0xFFFF0000u);
        int e = (h >> 2) & 15;
        xorperm8(w8, e & 7);
        int base = (q * 8) ^ (e & 8);
        *(uint4*)&tile[h][base]     = make_uint4(w8[0], w8[1], w8[2], w8[3]);
        *(uint4*)&tile[h][base + 4] = make_uint4(w8[4], w8[5], w8[6], w8[7]);
    }
    __syncthreads();

    // ---- LDS -> regs: logical cols w, w+8 (bank = (lane&1)*16 + cp: 2 lanes/bank, free) ----
    const int e4 = (lane >> 2) & 15;
    const int cp0 = w ^ e4;                    // physical col of logical w
    const __half2 sc = __float2half2_rn(0.03125f);
    __half2 v0[16], v1[16];
    #pragma unroll
    for (int r = 0; r < 16; r++) {
        v0[r] = __hmul2(u2h(tile[r * 64 + lane][cp0]),     sc);
        v1[r] = __hmul2(u2h(tile[r * 64 + lane][cp0 ^ 8]), sc);
    }

    // ---- WHT #1 ----
    wht16_h2(v0, lane);
    wht16_h2(v1, lane);

    // ---- rotation: v' = c2*v + s2*swap16(v) ----
    #pragma unroll
    for (int r = 0; r < 16; r++) {
        const int pr = __popc(r);
        unsigned int u0 = h2u(v0[r]), u1 = h2u(v1[r]);
        __half2 vs0 = u2h((u0 >> 16) | (u0 << 16));
        __half2 vs1 = u2h((u1 >> 16) | (u1 << 16));
        v0[r] = __hfma2(c2k[pr],     v0[r], __hmul2(s2k[pr],     vs0));
        v1[r] = __hfma2(c2k[pr + 1], v1[r], __hmul2(s2k[pr + 1], vs1));
    }

    // ---- WHT #2 ----
    wht16_h2(v0, lane);
    wht16_h2(v1, lane);

    // ---- regs -> LDS (own columns; ownership disjoint, no pre-barrier) ----
    #pragma unroll
    for (int r = 0; r < 16; r++) {
        tile[r * 64 + lane][cp0]     = h2u(v0[r]);
        tile[r * 64 + lane][cp0 ^ 8] = h2u(v1[r]);
    }
    __syncthreads();

    // ---- stage-out: inverse of stage-in ----
    #pragma unroll
    for (int it = 0; it < 4; it++) {
        int f = it * 512 + tid;
        int h = f >> 1, q = f & 1;
        int e = (h >> 2) & 15;
        int base = (q * 8) ^ (e & 8);
        uint4 u0 = *(const uint4*)&tile[h][base];
        uint4 u1 = *(const uint4*)&tile[h][base + 4];
        unsigned int w8[8] = {u0.x, u0.y, u0.z, u0.w, u1.x, u1.y, u1.z, u1.w};
        xorperm8(w8, e & 7);
        uint4 ra, ia;
        ra.x = (w8[0] & 0xFFFFu) | (w8[1] << 16);
        ia.x = (w8[0] >> 16)     | (w8[1] & 0xFFFF0000u);
        ra.y = (w8[2] & 0xFFFFu) | (w8[3] << 16);
        ia.y = (w8[2] >> 16)     | (w8[3] & 0xFFFF0000u);
        ra.z = (w8[4] & 0xFFFFu) | (w8[5] << 16);
        ia.z = (w8[4] >> 16)     | (w8[5] & 0xFFFF0000u);
        ra.w = (w8[6] & 0xFFFFu) | (w8[7] << 16);
        ia.w = (w8[6] >> 16)     | (w8[7] & 0xFFFF0000u);
        *(uint4*)(re + (size_t)h * 1024 + q * 8) = ra;
        *(uint4*)(im + (size_t)h * 1024 + q * 8) = ia;
    }
}

// ================= fp32 fallback (used only if ws too small) =================
__device__ __forceinline__ void wht10_f4(float4 v[4], int lane) {
    #pragma unroll
    for (int r = 0; r < 4; r++) {
        bf(v[r].x, v[r].y); bf(v[r].z, v[r].w);
        bf(v[r].x, v[r].z); bf(v[r].y, v[r].w);
    }
    #pragma unroll
    for (int m = 1; m <= 32; m <<= 1) {
        float sgn = (lane & m) ? -1.0f : 1.0f;
        #pragma unroll
        for (int r = 0; r < 4; r++) {
            float px = __shfl_xor(v[r].x, m), py = __shfl_xor(v[r].y, m);
            float pz = __shfl_xor(v[r].z, m), pw = __shfl_xor(v[r].w, m);
            v[r].x = fmaf(sgn, v[r].x, px); v[r].y = fmaf(sgn, v[r].y, py);
            v[r].z = fmaf(sgn, v[r].z, pz); v[r].w = fmaf(sgn, v[r].w, pw);
        }
    }
    bf(v[0].x, v[1].x); bf(v[0].y, v[1].y); bf(v[0].z, v[1].z); bf(v[0].w, v[1].w);
    bf(v[2].x, v[3].x); bf(v[2].y, v[3].y); bf(v[2].z, v[3].z); bf(v[2].w, v[3].w);
    bf(v[0].x, v[2].x); bf(v[0].y, v[2].y); bf(v[0].z, v[2].z); bf(v[0].w, v[2].w);
    bf(v[1].x, v[3].x); bf(v[1].y, v[3].y); bf(v[1].z, v[3].z); bf(v[1].w, v[3].w);
}

__global__ __launch_bounds__(256) void pass13_kernel(const float* __restrict__ srcA,
                                                     const float* __restrict__ srcB,
                                                     float* __restrict__ dst) {
    const int tid = threadIdx.x, lane = tid & 63, w = tid >> 6;
    const int rt0 = blockIdx.x * 16 + w * 4;
    const float* src = (rt0 < 16384) ? (srcA + (size_t)rt0 * 1024)
                                     : (srcB + (size_t)(rt0 - 16384) * 1024);
    float* d = dst + (size_t)rt0 * 1024;
    float4 v[4][4];
    #pragma unroll
    for (int rr = 0; rr < 4; rr++)
        #pragma unroll
        for (int r = 0; r < 4; r++)
            v[rr][r] = *(const float4*)(src + rr * 1024 + r * 256 + lane * 4);
    #pragma unroll
    for (int rr = 0; rr < 4; rr++) {
        wht10_f4(v[rr], lane);
        #pragma unroll
        for (int r = 0; r < 4; r++) {
            float4 o;
            o.x = v[rr][r].x * 0.03125f; o.y = v[rr][r].y * 0.03125f;
            o.z = v[rr][r].z * 0.03125f; o.w = v[rr][r].w * 0.03125f;
            *(float4*)(d + rr * 1024 + r * 256 + lane * 4) = o;
        }
    }
}

__global__ __launch_bounds__(256) void pass2f_kernel(float* __restrict__ out,
                                                     const float* __restrict__ tptr) {
    __shared__ __align__(16) float tile[2][1024][8];
    const int tid = threadIdx.x, lane = tid & 63, w = tid >> 6;
    int wg = blockIdx.x;
    int swz = (wg & 7) * 256 + (wg >> 3);
    const int b = swz >> 7, g = swz & 127;
    const int c0 = g * 8;
    const float tval = tptr[0];
    float* baseR = out + (size_t)b * DIMN;
    float* baseI = out + (size_t)16 * DIMN + (size_t)b * DIMN;
    float4 tmp[2][8];
    #pragma unroll
    for (int comp = 0; comp < 2; comp++) {
        const float* src = comp ? baseI : baseR;
        #pragma unroll
        for (int it = 0; it < 8; it++) {
            int f4id = it * 256 + tid;
            int h = f4id >> 1, q = f4id & 1;
            tmp[comp][it] = *(const float4*)(src + (size_t)h * 1024 + c0 + q * 4);
        }
    }
    #pragma unroll
    for (int comp = 0; comp < 2; comp++) {
        #pragma unroll
        for (int it = 0; it < 8; it++) {
            int f4id = it * 256 + tid;
            int h = f4id >> 1, q = f4id & 1;
            int e = (h >> 2) & 7, elo = e & 3;
            float4 val = tmp[comp][it];
            bool s0 = (elo & 1) != 0;
            float x1 = s0 ? val.y : val.x, y1 = s0 ? val.x : val.y;
            float z1 = s0 ? val.w : val.z, w1 = s0 ? val.z : val.w;
            bool s1 = (elo & 2) != 0;
            float x2 = s1 ? z1 : x1, y2 = s1 ? w1 : y1;
            float z2 = s1 ? x1 : z1, w2 = s1 ? y1 : w1;
            int qp = q ^ (e >> 2);
            *(float4*)&tile[comp][h][qp * 4] = make_float4(x2, y2, z2, w2);
        }
    }
    __syncthreads();
    float vr[2][16], vi[2][16];
    #pragma unroll
    for (int r = 0; r < 16; r++) {
        int h = r * 64 + lane;
        int e = (lane >> 2) & 7;
        #pragma unroll
        for (int cc = 0; cc < 2; cc++) {
            int cp = (2 * w + cc) ^ e;
            vr[cc][r] = tile[0][h][cp];
            vi[cc][r] = tile[1][h][cp];
        }
    }
    const int pcl = __popc(lane);
    #pragma unroll
    for (int cc = 0; cc < 2; cc++) {
        wht16_f32(vr[cc], lane);
        wht16_f32(vi[cc], lane);
        const int cg = c0 + 2 * w + cc;
        const int pbase = pcl + __popc(cg);
        float csk[5], snk[5];
        #pragma unroll
        for (int k = 0; k < 5; k++) {
            float ang = tval * (float)(20 - 2 * (pbase + k));
            __sincosf(ang, &snk[k], &csk[k]);
        }
        #pragma unroll
        for (int r = 0; r < 16; r++) {
            const int pr = __popc(r);
            float cv = csk[pr], sv = snk[pr];
            float xr = vr[cc][r] * 0.03125f, xi = vi[cc][r] * 0.03125f;
            vr[cc][r] = fmaf(cv, xr, sv * xi);
            vi[cc][r] = fmaf(cv, xi, -sv * xr);
        }
        wht16_f32(vr[cc], lane);
        wht16_f32(vi[cc], lane);
    }
    #pragma unroll
    for (int r = 0; r < 16; r++) {
        int h = r * 64 + lane;
        int e = (lane >> 2) & 7;
        #pragma unroll
        for (int cc = 0; cc < 2; cc++) {
            int cp = (2 * w + cc) ^ e;
            tile[0][h][cp] = vr[cc][r] * 0.03125f;
            tile[1][h][cp] = vi[cc][r] * 0.03125f;
        }
    }
    __syncthreads();
    #pragma unroll
    for (int comp = 0; comp < 2; comp++) {
        float* dstg = comp ? baseI : baseR;
        #pragma unroll
        for (int it = 0; it < 8; it++) {
            int f4id = it * 256 + tid;
            int h = f4id >> 1, q = f4id & 1;
            int e = (h >> 2) & 7, elo = e & 3;
            int qp = q ^ (e >> 2);
            float4 sv = *(const float4*)&tile[comp][h][qp * 4];
            bool s0 = (elo & 1) != 0;
            float x1 = s0 ? sv.y : sv.x, y1 = s0 ? sv.x : sv.y;
            float z1 = s0 ? sv.w : sv.z, w1 = s0 ? sv.z : sv.w;
            bool s1 = (elo & 2) != 0;
            float x2 = s1 ? z1 : x1, y2 = s1 ? w1 : y1;
            float z2 = s1 ? x1 : z1, w2 = s1 ? y1 : w1;
            *(float4*)(dstg + (size_t)h * 1024 + c0 + q * 4) = make_float4(x2, y2, z2, w2);
        }
    }
}

extern "C" void kernel_launch(void* const* d_in, const int* in_sizes, int n_in,
                              void* d_out, int out_size, void* d_ws, size_t ws_size,
                              hipStream_t stream) {
    const float* xr = (const float*)d_in[0];
    const float* xi = (const float*)d_in[1];
    const float* t  = (const float*)d_in[2];
    float* out = (float*)d_out;

    const size_t need = (size_t)2 * 16 * DIMN * sizeof(__half);  // 64 MiB
    if (ws_size >= need) {
        __half* ws = (__half*)d_ws;
        p1_kernel<<<4096, 256, 0, stream>>>(xr, xi, ws);
        p2_kernel<<<1024, 512, 0, stream>>>(ws, t);
        p3_kernel<<<4096, 256, 0, stream>>>(ws, out);
    } else {
        pass13_kernel<<<2048, 256, 0, stream>>>(xr, xi, out);
        pass2f_kernel<<<2048, 256, 0, stream>>>(out, t);
        pass13_kernel<<<2048, 256, 0, stream>>>(out, out + (size_t)16 * DIMN, out);
    }
}

// Round 9
// 97.224 us; speedup vs baseline: 1.8437x; 1.1743x over previous
//
#include <hip/hip_runtime.h>
#include <hip/hip_fp16.h>
#include <math.h>

#define DIMN (1 << 20)   // 2^20 per batch row
// d_out: [2][16][DIMN] f32.  d_ws: [16][DIMN] half2(re,im) interleaved (64 MiB).
// Factorization: H·D(t)·H = (H_l·D_l·H_l) ⊗ (H_h·D_h·H_h) since
// popc(i) = popc(l)+popc(h) -> D = D_l ⊗ D_h.  Pass A applies the low-bit
// operator along contiguous rows; Pass B the high-bit operator along stride-1024.

typedef unsigned int uint2v __attribute__((ext_vector_type(2)));

// ---------------- bit-cast helpers ----------------
__device__ __forceinline__ unsigned int h2u(__half2 v){ union{__half2 h; unsigned int u;} x; x.h=v; return x.u; }
__device__ __forceinline__ __half2 u2h(unsigned int v){ union{unsigned int u; __half2 h;} x; x.u=v; return x.h; }

__device__ __forceinline__ void bf(float& a, float& b) { float s = a + b; b = a - b; a = s; }

// ---------------- DPP lane-exchange (VALU pipe, not DS) ----------------
template<int CTRL>
__device__ __forceinline__ float dppf(float x) {
    return __int_as_float(__builtin_amdgcn_mov_dpp(__float_as_int(x), CTRL, 0xF, 0xF, true));
}
template<int CTRL>
__device__ __forceinline__ unsigned int dppu(unsigned int x) {
    return (unsigned int)__builtin_amdgcn_mov_dpp((int)x, CTRL, 0xF, 0xF, true);
}
__device__ __forceinline__ float xor4_f(float x) { return dppf<0x1B>(dppf<0x141>(x)); }
__device__ __forceinline__ unsigned int xor4_u(unsigned int x) { return dppu<0x1B>(dppu<0x141>(x)); }

// ---------------- permlane swap butterflies (VALU pipe) ----------------
__device__ __forceinline__ float bfly16_f(float x, float sgn) {
#if __has_builtin(__builtin_amdgcn_permlane16_swap)
    uint2v r = __builtin_amdgcn_permlane16_swap(__float_as_uint(x), __float_as_uint(x), false, false);
    return fmaf(sgn, __uint_as_float(r.y), __uint_as_float(r.x));
#else
    float p = __shfl_xor(x, 16);
    return fmaf(sgn, x, p);
#endif
}
__device__ __forceinline__ float bfly32_f(float x, float sgn) {
#if __has_builtin(__builtin_amdgcn_permlane32_swap)
    uint2v r = __builtin_amdgcn_permlane32_swap(__float_as_uint(x), __float_as_uint(x), false, false);
    return fmaf(sgn, __uint_as_float(r.y), __uint_as_float(r.x));
#else
    float p = __shfl_xor(x, 32);
    return fmaf(sgn, x, p);
#endif
}
__device__ __forceinline__ __half2 bfly16_h2(__half2 x, __half2 sgn) {
#if __has_builtin(__builtin_amdgcn_permlane16_swap)
    uint2v r = __builtin_amdgcn_permlane16_swap(h2u(x), h2u(x), false, false);
    return __hfma2(u2h(r.y), sgn, u2h(r.x));
#else
    __half2 p = u2h((unsigned)__shfl_xor((int)h2u(x), 16));
    return __hfma2(x, sgn, p);
#endif
}
__device__ __forceinline__ __half2 bfly32_h2(__half2 x, __half2 sgn) {
#if __has_builtin(__builtin_amdgcn_permlane32_swap)
    uint2v r = __builtin_amdgcn_permlane32_swap(h2u(x), h2u(x), false, false);
    return __hfma2(u2h(r.y), sgn, u2h(r.x));
#else
    __half2 p = u2h((unsigned)__shfl_xor((int)h2u(x), 32));
    return __hfma2(x, sgn, p);
#endif
}

// ---------------- f32 WHT over 10 bits (all-VALU lane exchange) ----------------
__device__ __forceinline__ void wht16_f32(float v[16], int lane) {
    #pragma unroll
    for (int s = 1; s < 16; s <<= 1)
        #pragma unroll
        for (int r = 0; r < 16; r++)
            if (!(r & s)) bf(v[r], v[r ^ s]);
    {   float sgn = (lane & 1) ? -1.0f : 1.0f;
        #pragma unroll
        for (int r = 0; r < 16; r++) { float p = dppf<0xB1>(v[r]); v[r] = fmaf(sgn, v[r], p); } }
    {   float sgn = (lane & 2) ? -1.0f : 1.0f;
        #pragma unroll
        for (int r = 0; r < 16; r++) { float p = dppf<0x4E>(v[r]); v[r] = fmaf(sgn, v[r], p); } }
    {   float sgn = (lane & 4) ? -1.0f : 1.0f;
        #pragma unroll
        for (int r = 0; r < 16; r++) { float p = xor4_f(v[r]); v[r] = fmaf(sgn, v[r], p); } }
    {   float sgn = (lane & 8) ? -1.0f : 1.0f;
        #pragma unroll
        for (int r = 0; r < 16; r++) { float p = dppf<0x128>(v[r]); v[r] = fmaf(sgn, v[r], p); } }
    {   float sgn = (lane & 16) ? -1.0f : 1.0f;
        #pragma unroll
        for (int r = 0; r < 16; r++) v[r] = bfly16_f(v[r], sgn); }
    {   float sgn = (lane & 32) ? -1.0f : 1.0f;
        #pragma unroll
        for (int r = 0; r < 16; r++) v[r] = bfly32_f(v[r], sgn); }
}

// ---------------- half2 (re,im)-packed WHT over 10 bits ----------------
__device__ __forceinline__ void wht16_h2(__half2 v[16], int lane) {
    #pragma unroll
    for (int s = 1; s < 16; s <<= 1)
        #pragma unroll
        for (int r = 0; r < 16; r++)
            if (!(r & s)) {
                __half2 t = __hadd2(v[r], v[r ^ s]);
                v[r ^ s]  = __hsub2(v[r], v[r ^ s]);
                v[r] = t;
            }
    {   __half2 sgn = __float2half2_rn((lane & 1) ? -1.0f : 1.0f);
        #pragma unroll
        for (int r = 0; r < 16; r++) { __half2 p = u2h(dppu<0xB1>(h2u(v[r]))); v[r] = __hfma2(v[r], sgn, p); } }
    {   __half2 sgn = __float2half2_rn((lane & 2) ? -1.0f : 1.0f);
        #pragma unroll
        for (int r = 0; r < 16; r++) { __half2 p = u2h(dppu<0x4E>(h2u(v[r]))); v[r] = __hfma2(v[r], sgn, p); } }
    {   __half2 sgn = __float2half2_rn((lane & 4) ? -1.0f : 1.0f);
        #pragma unroll
        for (int r = 0; r < 16; r++) { __half2 p = u2h(xor4_u(h2u(v[r]))); v[r] = __hfma2(v[r], sgn, p); } }
    {   __half2 sgn = __float2half2_rn((lane & 8) ? -1.0f : 1.0f);
        #pragma unroll
        for (int r = 0; r < 16; r++) { __half2 p = u2h(dppu<0x128>(h2u(v[r]))); v[r] = __hfma2(v[r], sgn, p); } }
    {   __half2 sgn = __float2half2_rn((lane & 16) ? -1.0f : 1.0f);
        #pragma unroll
        for (int r = 0; r < 16; r++) v[r] = bfly16_h2(v[r], sgn); }
    {   __half2 sgn = __float2half2_rn((lane & 32) ? -1.0f : 1.0f);
        #pragma unroll
        for (int r = 0; r < 16; r++) v[r] = bfly32_h2(v[r], sgn); }
}

// XOR-permute 4 words by m (0..3): a'[j] = a[j ^ m]
__device__ __forceinline__ void xorperm4(unsigned int a[4], int m) {
    bool s0 = (m & 1) != 0, s1 = (m & 2) != 0;
    unsigned int t0 = s0 ? a[1] : a[0], t1 = s0 ? a[0] : a[1];
    unsigned int t2 = s0 ? a[3] : a[2], t3 = s0 ? a[2] : a[3];
    a[0] = s1 ? t2 : t0; a[1] = s1 ? t3 : t1;
    a[2] = s1 ? t0 : t2; a[3] = s1 ? t1 : t3;
}

// XOR-permute 8 words by m (0..7): a'[j] = a[j ^ m]
__device__ __forceinline__ void xorperm8(unsigned int a[8], int m) {
    bool s0 = (m & 1) != 0, s1 = (m & 2) != 0, s2 = (m & 4) != 0;
    unsigned int b0 = s0 ? a[1] : a[0], b1 = s0 ? a[0] : a[1];
    unsigned int b2 = s0 ? a[3] : a[2], b3 = s0 ? a[2] : a[3];
    unsigned int b4 = s0 ? a[5] : a[4], b5 = s0 ? a[4] : a[5];
    unsigned int b6 = s0 ? a[7] : a[6], b7 = s0 ? a[6] : a[7];
    unsigned int c0 = s1 ? b2 : b0, c1 = s1 ? b3 : b1;
    unsigned int c2 = s1 ? b0 : b2, c3 = s1 ? b1 : b3;
    unsigned int c4 = s1 ? b6 : b4, c5 = s1 ? b7 : b5;
    unsigned int c6 = s1 ? b4 : b6, c7 = s1 ? b5 : b7;
    a[0] = s2 ? c4 : c0; a[1] = s2 ? c5 : c1;
    a[2] = s2 ? c6 : c2; a[3] = s2 ? c7 : c3;
    a[4] = s2 ? c0 : c4; a[5] = s2 ? c1 : c5;
    a[6] = s2 ? c2 : c6; a[7] = s2 ? c3 : c7;
}

// ================= Pass A: f32 in -> (H_l D_l H_l) -> fp16 half2(re,im) ws =================
// Element l = q*512 + lane*8 + s (reg r = q*8+s); popc(l) = popc(lane) + popc(r).
__global__ __launch_bounds__(256, 4) void pA_kernel(const float* __restrict__ xr,
                                                    const float* __restrict__ xi,
                                                    __half2* __restrict__ ws,
                                                    const float* __restrict__ tptr) {
    const int tid = threadIdx.x, lane = tid & 63, w = tid >> 6;
    const int rt = blockIdx.x * 4 + w;             // (batch*1024 + h) in [0,16384)
    const float tval = tptr[0];
    const int pcl = __popc(lane);
    float cs[5], sn[5];
    #pragma unroll
    for (int k = 0; k < 5; k++) {
        float ang = tval * (float)(10 - 2 * (pcl + k));
        float s, c;
        __sincosf(ang, &s, &c);
        cs[k] = c * 0.03125f;                      // fold 2^-5 for WHT #2
        sn[k] = s * 0.03125f;
    }
    const float* re = xr + (size_t)rt * 1024;
    const float* im = xi + (size_t)rt * 1024;
    float vr[16], vi[16];
    #pragma unroll
    for (int q = 0; q < 2; q++) {
        const int base = q * 512 + lane * 8;
        float4 a0 = *(const float4*)(re + base);
        float4 a1 = *(const float4*)(re + base + 4);
        float4 b0 = *(const float4*)(im + base);
        float4 b1 = *(const float4*)(im + base + 4);
        vr[q*8+0]=a0.x*0.03125f; vr[q*8+1]=a0.y*0.03125f; vr[q*8+2]=a0.z*0.03125f; vr[q*8+3]=a0.w*0.03125f;
        vr[q*8+4]=a1.x*0.03125f; vr[q*8+5]=a1.y*0.03125f; vr[q*8+6]=a1.z*0.03125f; vr[q*8+7]=a1.w*0.03125f;
        vi[q*8+0]=b0.x*0.03125f; vi[q*8+1]=b0.y*0.03125f; vi[q*8+2]=b0.z*0.03125f; vi[q*8+3]=b0.w*0.03125f;
        vi[q*8+4]=b1.x*0.03125f; vi[q*8+5]=b1.y*0.03125f; vi[q*8+6]=b1.z*0.03125f; vi[q*8+7]=b1.w*0.03125f;
    }
    wht16_f32(vr, lane);
    wht16_f32(vi, lane);
    #pragma unroll
    for (int r = 0; r < 16; r++) {
        const int pr = __popc(r);                  // popc of element bits in regs
        float x = vr[r], y = vi[r];
        vr[r] = fmaf(cs[pr], x,  sn[pr] * y);      // c*xr + s*xi
        vi[r] = fmaf(cs[pr], y, -sn[pr] * x);      // c*xi - s*xr
    }
    wht16_f32(vr, lane);
    wht16_f32(vi, lane);
    __half2* wp = ws + (size_t)rt * 1024;
    #pragma unroll
    for (int q = 0; q < 2; q++) {
        const int base = q * 512 + lane * 8;
        uint4 u0, u1;
        u0.x = h2u(__floats2half2_rn(vr[q*8+0], vi[q*8+0]));
        u0.y = h2u(__floats2half2_rn(vr[q*8+1], vi[q*8+1]));
        u0.z = h2u(__floats2half2_rn(vr[q*8+2], vi[q*8+2]));
        u0.w = h2u(__floats2half2_rn(vr[q*8+3], vi[q*8+3]));
        u1.x = h2u(__floats2half2_rn(vr[q*8+4], vi[q*8+4]));
        u1.y = h2u(__floats2half2_rn(vr[q*8+5], vi[q*8+5]));
        u1.z = h2u(__floats2half2_rn(vr[q*8+6], vi[q*8+6]));
        u1.w = h2u(__floats2half2_rn(vr[q*8+7], vi[q*8+7]));
        *(uint4*)(wp + base)     = u0;
        *(uint4*)(wp + base + 4) = u1;
    }
}

// ================= Pass B: fp16 ws -> (H_h D_h H_h) -> f32 out =================
// Tile: [1024 h][16 cols] half2 = 64 KiB LDS. 512 threads; wave w owns logical
// cols {w, w+8}. Physical col = logical ^ ((h>>2)&15). Rotation depends only on
// popc(h) = popc(lane)+popc(r) -> one 5-entry table for both columns.
__global__ __launch_bounds__(512, 4) void pB_kernel(const __half2* __restrict__ ws,
                                                    float* __restrict__ out,
                                                    const float* __restrict__ tptr) {
    __shared__ unsigned int tile[1024][16];
    const int tid = threadIdx.x, lane = tid & 63, w = tid >> 6;

    // XCD-chunked bijective swizzle (1024 % 8 == 0)
    int wg  = blockIdx.x;
    int swz = (wg & 7) * 128 + (wg >> 3);
    const int b  = swz >> 6;           // batch 0..15
    const int g  = swz & 63;           // column group 0..63
    const int c0 = g * 16;
    const float tval = tptr[0];

    const int pcl = __popc(lane);
    __half2 c2k[5], s2k[5];
    #pragma unroll
    for (int k = 0; k < 5; k++) {
        float ang = tval * (float)(10 - 2 * (pcl + k));
        float s, c;
        __sincosf(ang, &s, &c);
        c2k[k] = __float2half2_rn(c * 0.03125f);                 // (c', c')
        s2k[k] = __halves2half2(__float2half(s * 0.03125f),
                                __float2half(-s * 0.03125f));    // (s', -s')
    }

    const __half2* src = ws + (size_t)b * DIMN + c0;

    // ---- stage-in: item f=(h, quad); 64 B contiguous per row, 16 rows/wave-load ----
    #pragma unroll
    for (int it = 0; it < 8; it++) {
        int f = it * 512 + tid;                // 0..4095
        int h = f >> 2, qd = f & 3;
        uint4 a = *(const uint4*)(src + (size_t)h * 1024 + qd * 4);
        unsigned int g4[4] = {a.x, a.y, a.z, a.w};
        int e = (h >> 2) & 15;
        xorperm4(g4, e & 3);
        int dq = qd ^ (e >> 2);
        *(uint4*)&tile[h][dq * 4] = make_uint4(g4[0], g4[1], g4[2], g4[3]);
    }
    __syncthreads();

    // ---- LDS -> regs: logical cols w, w+8 (2 lanes/bank, conflict-free) ----
    const int e4 = (lane >> 2) & 15;
    const int cp0 = w ^ e4;
    const __half2 sc = __float2half2_rn(0.03125f);
    __half2 v0[16], v1[16];
    #pragma unroll
    for (int r = 0; r < 16; r++) {
        v0[r] = __hmul2(u2h(tile[r * 64 + lane][cp0]),     sc);
        v1[r] = __hmul2(u2h(tile[r * 64 + lane][cp0 ^ 8]), sc);
    }

    // ---- WHT #1 ----
    wht16_h2(v0, lane);
    wht16_h2(v1, lane);

    // ---- rotation (same table for both cols): v' = c2*v + s2*swap16(v) ----
    #pragma unroll
    for (int r = 0; r < 16; r++) {
        const int pr = __popc(r);
        unsigned int u0 = h2u(v0[r]), u1 = h2u(v1[r]);
        __half2 vs0 = u2h((u0 >> 16) | (u0 << 16));
        __half2 vs1 = u2h((u1 >> 16) | (u1 << 16));
        v0[r] = __hfma2(c2k[pr], v0[r], __hmul2(s2k[pr], vs0));
        v1[r] = __hfma2(c2k[pr], v1[r], __hmul2(s2k[pr], vs1));
    }

    // ---- WHT #2 ----
    wht16_h2(v0, lane);
    wht16_h2(v1, lane);

    // ---- regs -> LDS (own columns; disjoint, no pre-barrier) ----
    #pragma unroll
    for (int r = 0; r < 16; r++) {
        tile[r * 64 + lane][cp0]     = h2u(v0[r]);
        tile[r * 64 + lane][cp0 ^ 8] = h2u(v1[r]);
    }
    __syncthreads();

    // ---- stage-out: unpack half2 -> f32 re/im planes of d_out ----
    float* outR = out + (size_t)b * DIMN + c0;
    float* outI = out + (size_t)16 * DIMN + (size_t)b * DIMN + c0;
    #pragma unroll
    for (int it = 0; it < 4; it++) {
        int f = it * 512 + tid;                // 0..2047
        int h = f >> 1, q8 = f & 1;
        int e = (h >> 2) & 15;
        int base = (q8 ^ (e >> 3)) * 8;
        uint4 u0 = *(const uint4*)&tile[h][base];
        uint4 u1 = *(const uint4*)&tile[h][base + 4];
        unsigned int w8[8] = {u0.x, u0.y, u0.z, u0.w, u1.x, u1.y, u1.z, u1.w};
        xorperm8(w8, e & 7);
        float4 r0, r1, i0, i1;
        r0.x = __low2float(u2h(w8[0])); i0.x = __high2float(u2h(w8[0]));
        r0.y = __low2float(u2h(w8[1])); i0.y = __high2float(u2h(w8[1]));
        r0.z = __low2float(u2h(w8[2])); i0.z = __high2float(u2h(w8[2]));
        r0.w = __low2float(u2h(w8[3])); i0.w = __high2float(u2h(w8[3]));
        r1.x = __low2float(u2h(w8[4])); i1.x = __high2float(u2h(w8[4]));
        r1.y = __low2float(u2h(w8[5])); i1.y = __high2float(u2h(w8[5]));
        r1.z = __low2float(u2h(w8[6])); i1.z = __high2float(u2h(w8[6]));
        r1.w = __low2float(u2h(w8[7])); i1.w = __high2float(u2h(w8[7]));
        size_t off = (size_t)h * 1024 + q8 * 8;
        *(float4*)(outR + off)     = r0;
        *(float4*)(outR + off + 4) = r1;
        *(float4*)(outI + off)     = i0;
        *(float4*)(outI + off + 4) = i1;
    }
}

// ================= fp32 fallback (3-pass, used only if ws too small) =================
__device__ __forceinline__ void wht10_f4(float4 v[4], int lane) {
    #pragma unroll
    for (int r = 0; r < 4; r++) {
        bf(v[r].x, v[r].y); bf(v[r].z, v[r].w);
        bf(v[r].x, v[r].z); bf(v[r].y, v[r].w);
    }
    #pragma unroll
    for (int m = 1; m <= 32; m <<= 1) {
        float sgn = (lane & m) ? -1.0f : 1.0f;
        #pragma unroll
        for (int r = 0; r < 4; r++) {
            float px = __shfl_xor(v[r].x, m), py = __shfl_xor(v[r].y, m);
            float pz = __shfl_xor(v[r].z, m), pw = __shfl_xor(v[r].w, m);
            v[r].x = fmaf(sgn, v[r].x, px); v[r].y = fmaf(sgn, v[r].y, py);
            v[r].z = fmaf(sgn, v[r].z, pz); v[r].w = fmaf(sgn, v[r].w, pw);
        }
    }
    bf(v[0].x, v[1].x); bf(v[0].y, v[1].y); bf(v[0].z, v[1].z); bf(v[0].w, v[1].w);
    bf(v[2].x, v[3].x); bf(v[2].y, v[3].y); bf(v[2].z, v[3].z); bf(v[2].w, v[3].w);
    bf(v[0].x, v[2].x); bf(v[0].y, v[2].y); bf(v[0].z, v[2].z); bf(v[0].w, v[2].w);
    bf(v[1].x, v[3].x); bf(v[1].y, v[3].y); bf(v[1].z, v[3].z); bf(v[1].w, v[3].w);
}

__global__ __launch_bounds__(256) void pass13_kernel(const float* __restrict__ srcA,
                                                     const float* __restrict__ srcB,
                                                     float* __restrict__ dst) {
    const int tid = threadIdx.x, lane = tid & 63, w = tid >> 6;
    const int rt0 = blockIdx.x * 16 + w * 4;
    const float* src = (rt0 < 16384) ? (srcA + (size_t)rt0 * 1024)
                                     : (srcB + (size_t)(rt0 - 16384) * 1024);
    float* d = dst + (size_t)rt0 * 1024;
    float4 v[4][4];
    #pragma unroll
    for (int rr = 0; rr < 4; rr++)
        #pragma unroll
        for (int r = 0; r < 4; r++)
            v[rr][r] = *(const float4*)(src + rr * 1024 + r * 256 + lane * 4);
    #pragma unroll
    for (int rr = 0; rr < 4; rr++) {
        wht10_f4(v[rr], lane);
        #pragma unroll
        for (int r = 0; r < 4; r++) {
            float4 o;
            o.x = v[rr][r].x * 0.03125f; o.y = v[rr][r].y * 0.03125f;
            o.z = v[rr][r].z * 0.03125f; o.w = v[rr][r].w * 0.03125f;
            *(float4*)(d + rr * 1024 + r * 256 + lane * 4) = o;
        }
    }
}

__global__ __launch_bounds__(256) void pass2f_kernel(float* __restrict__ out,
                                                     const float* __restrict__ tptr) {
    __shared__ __align__(16) float tile[2][1024][8];
    const int tid = threadIdx.x, lane = tid & 63, w = tid >> 6;
    int wg = blockIdx.x;
    int swz = (wg & 7) * 256 + (wg >> 3);
    const int b = swz >> 7, g = swz & 127;
    const int c0 = g * 8;
    const float tval = tptr[0];
    float* baseR = out + (size_t)b * DIMN;
    float* baseI = out + (size_t)16 * DIMN + (size_t)b * DIMN;
    float4 tmp[2][8];
    #pragma unroll
    for (int comp = 0; comp < 2; comp++) {
        const float* src = comp ? baseI : baseR;
        #pragma unroll
        for (int it = 0; it < 8; it++) {
            int f4id = it * 256 + tid;
            int h = f4id >> 1, q = f4id & 1;
            tmp[comp][it] = *(const float4*)(src + (size_t)h * 1024 + c0 + q * 4);
        }
    }
    #pragma unroll
    for (int comp = 0; comp < 2; comp++) {
        #pragma unroll
        for (int it = 0; it < 8; it++) {
            int f4id = it * 256 + tid;
            int h = f4id >> 1, q = f4id & 1;
            int e = (h >> 2) & 7, elo = e & 3;
            float4 val = tmp[comp][it];
            bool s0 = (elo & 1) != 0;
            float x1 = s0 ? val.y : val.x, y1 = s0 ? val.x : val.y;
            float z1 = s0 ? val.w : val.z, w1 = s0 ? val.z : val.w;
            bool s1 = (elo & 2) != 0;
            float x2 = s1 ? z1 : x1, y2 = s1 ? w1 : y1;
            float z2 = s1 ? x1 : z1, w2 = s1 ? y1 : w1;
            int qp = q ^ (e >> 2);
            *(float4*)&tile[comp][h][qp * 4] = make_float4(x2, y2, z2, w2);
        }
    }
    __syncthreads();
    float vr[2][16], vi[2][16];
    #pragma unroll
    for (int r = 0; r < 16; r++) {
        int h = r * 64 + lane;
        int e = (lane >> 2) & 7;
        #pragma unroll
        for (int cc = 0; cc < 2; cc++) {
            int cp = (2 * w + cc) ^ e;
            vr[cc][r] = tile[0][h][cp];
            vi[cc][r] = tile[1][h][cp];
        }
    }
    const int pcl = __popc(lane);
    #pragma unroll
    for (int cc = 0; cc < 2; cc++) {
        wht16_f32(vr[cc], lane);
        wht16_f32(vi[cc], lane);
        const int cg = c0 + 2 * w + cc;
        const int pbase = pcl + __popc(cg);
        float csk[5], snk[5];
        #pragma unroll
        for (int k = 0; k < 5; k++) {
            float ang = tval * (float)(20 - 2 * (pbase + k));
            __sincosf(ang, &snk[k], &csk[k]);
        }
        #pragma unroll
        for (int r = 0; r < 16; r++) {
            const int pr = __popc(r);
            float cv = csk[pr], sv = snk[pr];
            float xr = vr[cc][r] * 0.03125f, xi = vi[cc][r] * 0.03125f;
            vr[cc][r] = fmaf(cv, xr, sv * xi);
            vi[cc][r] = fmaf(cv, xi, -sv * xr);
        }
        wht16_f32(vr[cc], lane);
        wht16_f32(vi[cc], lane);
    }
    #pragma unroll
    for (int r = 0; r < 16; r++) {
        int h = r * 64 + lane;
        int e = (lane >> 2) & 7;
        #pragma unroll
        for (int cc = 0; cc < 2; cc++) {
            int cp = (2 * w + cc) ^ e;
            tile[0][h][cp] = vr[cc][r] * 0.03125f;
            tile[1][h][cp] = vi[cc][r] * 0.03125f;
        }
    }
    __syncthreads();
    #pragma unroll
    for (int comp = 0; comp < 2; comp++) {
        float* dstg = comp ? baseI : baseR;
        #pragma unroll
        for (int it = 0; it < 8; it++) {
            int f4id = it * 256 + tid;
            int h = f4id >> 1, q = f4id & 1;
            int e = (h >> 2) & 7, elo = e & 3;
            int qp = q ^ (e >> 2);
            float4 sv = *(const float4*)&tile[comp][h][qp * 4];
            bool s0 = (elo & 1) != 0;
            float x1 = s0 ? sv.y : sv.x, y1 = s0 ? sv.x : sv.y;
            float z1 = s0 ? sv.w : sv.z, w1 = s0 ? sv.z : sv.w;
            bool s1 = (elo & 2) != 0;
            float x2 = s1 ? z1 : x1, y2 = s1 ? w1 : y1;
            float z2 = s1 ? x1 : z1, w2 = s1 ? y1 : w1;
            *(float4*)(dstg + (size_t)h * 1024 + c0 + q * 4) = make_float4(x2, y2, z2, w2);
        }
    }
}

extern "C" void kernel_launch(void* const* d_in, const int* in_sizes, int n_in,
                              void* d_out, int out_size, void* d_ws, size_t ws_size,
                              hipStream_t stream) {
    const float* xr = (const float*)d_in[0];
    const float* xi = (const float*)d_in[1];
    const float* t  = (const float*)d_in[2];
    float* out = (float*)d_out;

    const size_t need = (size_t)16 * DIMN * sizeof(__half2);  // 64 MiB interleaved
    if (ws_size >= need) {
        __half2* ws = (__half2*)d_ws;
        pA_kernel<<<4096, 256, 0, stream>>>(xr, xi, ws, t);
        pB_kernel<<<1024, 512, 0, stream>>>(ws, out, t);
    } else {
        pass13_kernel<<<2048, 256, 0, stream>>>(xr, xi, out);
        pass2f_kernel<<<2048, 256, 0, stream>>>(out, t);
        pass13_kernel<<<2048, 256, 0, stream>>>(out, out + (size_t)16 * DIMN, out);
    }
}